// Round 11
// baseline (1662.213 us; speedup 1.0000x reference)
//
#include <hip/hip_runtime.h>
#include <cstddef>

constexpr int B_   = 64;
constexpr int P_   = 196;
constexpr int ENC_ = 2048;
constexpr int ATT_ = 512;
constexpr int DEC_ = 512;
constexpr int EMB_ = 512;
constexpr int V_   = 10000;
constexpr int MAXLEN_ = 30;
constexpr int T_   = 29;
constexpr int G4_  = 2048;
constexpr int KIH_ = 2560;          // W_ih row length (emb|ctx)
constexpr int XK2_ = 2560;          // loop xcat: ctx(2048) | h(512)

constexpr int NBLK = 256;
constexpr int TPB  = 1024;
constexpr int NT   = NBLK * TPB;
constexpr int NW   = NT / 64;       // 4096 waves
constexpr int FSTR = 16;            // flag stride (dwords) = 64B
constexpr size_t ZS_ = (size_t)B_ * G4_;   // one z-slice of gp (floats)
constexpr int NPT = 625;            // preds tasks (10000/16)

typedef __attribute__((ext_vector_type(8))) short short8;
typedef __attribute__((ext_vector_type(4))) float f32x4;
using us = unsigned short;

__device__ __forceinline__ us f2bf(float x) {
    union { float f; unsigned u; } v; v.f = x;
    unsigned r = v.u + 0x7fff + ((v.u >> 16) & 1);
    return (us)(r >> 16);
}
__device__ __forceinline__ float bf2f(us u) {
    union { unsigned u; float f; } v; v.u = ((unsigned)u) << 16;
    return v.f;
}

// ---- agent-scope (sc1) L2-bypassing access helpers -------------------------
__device__ __forceinline__ unsigned ld4cc(const void* p) {
    unsigned r;
    asm volatile("global_load_dword %0, %1, off sc1\n\ts_waitcnt vmcnt(0)"
                 : "=v"(r) : "v"(p) : "memory");
    return r;
}
__device__ __forceinline__ void ld4cc_x8(const float* p0, const float* p1,
                                         const float* p2, const float* p3,
                                         const float* p4, const float* p5,
                                         const float* p6, const float* p7,
                                         float* o) {
    float r0, r1, r2, r3, r4, r5, r6, r7;
    asm volatile("global_load_dword %0, %8, off sc1\n\t"
                 "global_load_dword %1, %9, off sc1\n\t"
                 "global_load_dword %2, %10, off sc1\n\t"
                 "global_load_dword %3, %11, off sc1\n\t"
                 "global_load_dword %4, %12, off sc1\n\t"
                 "global_load_dword %5, %13, off sc1\n\t"
                 "global_load_dword %6, %14, off sc1\n\t"
                 "global_load_dword %7, %15, off sc1\n\t"
                 "s_waitcnt vmcnt(0)"
                 : "=&v"(r0), "=&v"(r1), "=&v"(r2), "=&v"(r3),
                   "=&v"(r4), "=&v"(r5), "=&v"(r6), "=&v"(r7)
                 : "v"(p0), "v"(p1), "v"(p2), "v"(p3),
                   "v"(p4), "v"(p5), "v"(p6), "v"(p7) : "memory");
    o[0]=r0; o[1]=r1; o[2]=r2; o[3]=r3; o[4]=r4; o[5]=r5; o[6]=r6; o[7]=r7;
}
__device__ __forceinline__ void ld16cc_x3(const void* p0, const void* p1, const void* p2,
                                          short8* a, short8* b, short8* c) {
    short8 ra, rb, rc;
    asm volatile("global_load_dwordx4 %0, %3, off sc1\n\t"
                 "global_load_dwordx4 %1, %4, off sc1\n\t"
                 "global_load_dwordx4 %2, %5, off sc1\n\t"
                 "s_waitcnt vmcnt(0)"
                 : "=&v"(ra), "=&v"(rb), "=&v"(rc)
                 : "v"(p0), "v"(p1), "v"(p2) : "memory");
    *a = ra; *b = rb; *c = rc;
}
__device__ __forceinline__ void ld16cc_x4(const void* p0, const void* p1,
                                          const void* p2, const void* p3,
                                          short8* a, short8* b, short8* c, short8* d) {
    short8 ra, rb, rc, rd;
    asm volatile("global_load_dwordx4 %0, %4, off sc1\n\t"
                 "global_load_dwordx4 %1, %5, off sc1\n\t"
                 "global_load_dwordx4 %2, %6, off sc1\n\t"
                 "global_load_dwordx4 %3, %7, off sc1\n\t"
                 "s_waitcnt vmcnt(0)"
                 : "=&v"(ra), "=&v"(rb), "=&v"(rc), "=&v"(rd)
                 : "v"(p0), "v"(p1), "v"(p2), "v"(p3) : "memory");
    *a = ra; *b = rb; *c = rc; *d = rd;
}
__device__ __forceinline__ void ldf8cc(const void* p0, const void* p1, f32x4* a, f32x4* b) {
    f32x4 ra, rb;
    asm volatile("global_load_dwordx4 %0, %2, off sc1\n\t"
                 "global_load_dwordx4 %1, %3, off sc1\n\t"
                 "s_waitcnt vmcnt(0)"
                 : "=&v"(ra), "=&v"(rb) : "v"(p0), "v"(p1) : "memory");
    *a = ra; *b = rb;
}
// batched PLAIN (L2-cached) 16B loads: all loads + wait in ONE asm block
__device__ __forceinline__ void ldg7(const us* p0, const us* p1, const us* p2,
                                     const us* p3, const us* p4, const us* p5,
                                     const us* p6, short8* o) {
    short8 r0, r1, r2, r3, r4, r5, r6;
    asm volatile("global_load_dwordx4 %0, %7, off\n\t"
                 "global_load_dwordx4 %1, %8, off\n\t"
                 "global_load_dwordx4 %2, %9, off\n\t"
                 "global_load_dwordx4 %3, %10, off\n\t"
                 "global_load_dwordx4 %4, %11, off\n\t"
                 "global_load_dwordx4 %5, %12, off\n\t"
                 "global_load_dwordx4 %6, %13, off\n\t"
                 "s_waitcnt vmcnt(0)"
                 : "=&v"(r0), "=&v"(r1), "=&v"(r2), "=&v"(r3),
                   "=&v"(r4), "=&v"(r5), "=&v"(r6)
                 : "v"(p0), "v"(p1), "v"(p2), "v"(p3),
                   "v"(p4), "v"(p5), "v"(p6) : "memory");
    o[0]=r0; o[1]=r1; o[2]=r2; o[3]=r3; o[4]=r4; o[5]=r5; o[6]=r6;
}
__device__ __forceinline__ void ldg6(const us* p0, const us* p1, const us* p2,
                                     const us* p3, const us* p4, const us* p5,
                                     short8* o) {
    short8 r0, r1, r2, r3, r4, r5;
    asm volatile("global_load_dwordx4 %0, %6, off\n\t"
                 "global_load_dwordx4 %1, %7, off\n\t"
                 "global_load_dwordx4 %2, %8, off\n\t"
                 "global_load_dwordx4 %3, %9, off\n\t"
                 "global_load_dwordx4 %4, %10, off\n\t"
                 "global_load_dwordx4 %5, %11, off\n\t"
                 "s_waitcnt vmcnt(0)"
                 : "=&v"(r0), "=&v"(r1), "=&v"(r2), "=&v"(r3),
                   "=&v"(r4), "=&v"(r5)
                 : "v"(p0), "v"(p1), "v"(p2), "v"(p3),
                   "v"(p4), "v"(p5) : "memory");
    o[0]=r0; o[1]=r1; o[2]=r2; o[3]=r3; o[4]=r4; o[5]=r5;
}
__device__ __forceinline__ void st4cc(void* p, unsigned v) {
    asm volatile("global_store_dword %0, %1, off sc1" :: "v"(p), "v"(v) : "memory");
}
__device__ __forceinline__ void st2cc(void* p, unsigned v) {
    asm volatile("global_store_short %0, %1, off sc1" :: "v"(p), "v"(v) : "memory");
}
__device__ __forceinline__ float wredsum(float a) {
#pragma unroll
    for (int o = 32; o > 0; o >>= 1) a += __shfl_xor(a, o);
    return a;
}

// all-to-all barrier, split into arrive / wait.
template<bool REL>
__device__ __forceinline__ void gbar_arrive(unsigned* flags, unsigned tok) {
    asm volatile("s_waitcnt vmcnt(0)" ::: "memory");
    __syncthreads();
    if (threadIdx.x == 0)
        __hip_atomic_store(&flags[blockIdx.x * FSTR], tok,
                           REL ? __ATOMIC_RELEASE : __ATOMIC_RELAXED,
                           __HIP_MEMORY_SCOPE_AGENT);
}
__device__ __forceinline__ void gbar_wait(unsigned* flags, unsigned tok) {
    if (threadIdx.x < NBLK) {
        while (__hip_atomic_load(&flags[threadIdx.x * FSTR], __ATOMIC_RELAXED,
                                 __HIP_MEMORY_SCOPE_AGENT) < tok)
            __builtin_amdgcn_s_sleep(1);
    }
    __syncthreads();
}
template<bool REL>
__device__ __forceinline__ void gbar(unsigned* flags, unsigned tok) {
    gbar_arrive<REL>(flags, tok);
    gbar_wait(flags, tok);
}

__device__ __forceinline__ void cvt8(const float* __restrict__ src, us* __restrict__ dst) {
    const float4* p = (const float4*)src;
    float4 a = p[0], b = p[1];
    union { short8 v; us u[8]; } o;
    o.u[0] = f2bf(a.x); o.u[1] = f2bf(a.y); o.u[2] = f2bf(a.z); o.u[3] = f2bf(a.w);
    o.u[4] = f2bf(b.x); o.u[5] = f2bf(b.y); o.u[6] = f2bf(b.z); o.u[7] = f2bf(b.w);
    *(short8*)dst = o.v;
}

__device__ __forceinline__ float score8(short8 v, const f32x4& lo, const f32x4& hi,
                                        const float4& w0, const float4& w1) {
    float acc = 0.f, x;
    x = bf2f((us)v[0]) + lo[0]; acc += fmaxf(x, 0.f) * w0.x;
    x = bf2f((us)v[1]) + lo[1]; acc += fmaxf(x, 0.f) * w0.y;
    x = bf2f((us)v[2]) + lo[2]; acc += fmaxf(x, 0.f) * w0.z;
    x = bf2f((us)v[3]) + lo[3]; acc += fmaxf(x, 0.f) * w0.w;
    x = bf2f((us)v[4]) + hi[0]; acc += fmaxf(x, 0.f) * w1.x;
    x = bf2f((us)v[5]) + hi[1]; acc += fmaxf(x, 0.f) * w1.y;
    x = bf2f((us)v[6]) + hi[2]; acc += fmaxf(x, 0.f) * w1.z;
    x = bf2f((us)v[7]) + hi[3]; acc += fmaxf(x, 0.f) * w1.w;
    return acc;
}

// preds task: 64x16 output tile, A (h snapshot) from LDS, B = wfcb rows.
__device__ __forceinline__ void preds_task(const us* s_h, const us* __restrict__ wfcb,
                                           const float* __restrict__ b_fc,
                                           float* __restrict__ outp,
                                           int nt, int tt, int lane) {
    const int r = lane & 15, g = lane >> 4;
    f32x4 acc[4] = {{0,0,0,0},{0,0,0,0},{0,0,0,0},{0,0,0,0}};
    const us* Brow = wfcb + (size_t)(nt*16 + r)*DEC_ + g*8;
    const us* As   = s_h + r*520 + g*8;
#pragma unroll
    for (int k0 = 0; k0 < DEC_; k0 += 64) {
        short8 b0 = *(const short8*)(Brow + k0);
        short8 b1 = *(const short8*)(Brow + k0 + 32);
#pragma unroll
        for (int mt = 0; mt < 4; ++mt) {
            short8 a0 = *(const short8*)(As + mt*16*520 + k0);
            short8 a1 = *(const short8*)(As + mt*16*520 + k0 + 32);
            acc[mt] = __builtin_amdgcn_mfma_f32_16x16x32_bf16(a0, b0, acc[mt], 0, 0, 0);
            acc[mt] = __builtin_amdgcn_mfma_f32_16x16x32_bf16(a1, b1, acc[mt], 0, 0, 0);
        }
    }
    const int n = nt*16 + r;
    const float bv = b_fc[n];
#pragma unroll
    for (int mt = 0; mt < 4; ++mt)
#pragma unroll
        for (int i = 0; i < 4; ++i) {
            int b = mt*16 + g*4 + i;
            outp[(size_t)b*(T_*V_) + (size_t)tt*V_ + n] = acc[mt][i] + bv;
        }
}

__global__ __launch_bounds__(TPB)
void k_persist(
    const float* __restrict__ enc, const int* __restrict__ captions,
    const float* __restrict__ emb_table,
    const float* __restrict__ W_enc_att, const float* __restrict__ b_enc_att,
    const float* __restrict__ W_dec_att, const float* __restrict__ b_dec_att,
    const float* __restrict__ w_full,
    const float* __restrict__ W_ih, const float* __restrict__ b_ih,
    const float* __restrict__ W_hh, const float* __restrict__ b_hh,
    const float* __restrict__ W_init_h, const float* __restrict__ b_init_h,
    const float* __restrict__ W_init_c, const float* __restrict__ b_init_c,
    const float* __restrict__ W_fc, const float* __restrict__ b_fc,
    us* encb, us* wencb, us* wdecb, us* wfcb, us* wcat2, us* wembW,
    us* winitb, us* xembA, us* att1b, us* hbuf, us* xcatb, us* meanbb,
    float* cst, float* att2G, float* gp, float* gpe, float* bsum,
    unsigned* flags, float* outp, float* outa)
{
    __shared__ us s_stage[64 * 520];          // staging / fold buffer (66.5 KB)
    __shared__ us s_wb[64 * 328];             // persistent wcat2 slice (41 KB)
    __shared__ us s_wd[16 * 520];             // persistent wdec slice (16.6 KB, bid<32)
    __shared__ float s_e[P_];
    __shared__ float s_al[P_];
    __shared__ float s_red[32];

    const int tid = threadIdx.x, bid = blockIdx.x;
    const int gtid = bid * TPB + tid;
    const int wid  = gtid >> 6;
    const int w    = tid >> 6;
    const int lane = tid & 63;
    unsigned tok = 0;
    float creg = 0.f;                          // persistent LSTM cell state
    us* const hb0 = hbuf;                      // h(t) for even t
    us* const hb1 = hbuf + (size_t)B_ * DEC_;  // h(t) for odd t; h0 lives here
    unsigned* const aflags = flags + (NBLK + 16) * FSTR;   // att2 producer flags (32)

    // ---------------- S0a: bf16 casts + bias-sum + mean + xembA gather ----------------
    for (int i = gtid; i < B_*P_*ENC_/8; i += NT) cvt8(enc + (size_t)i*8, encb + (size_t)i*8);
    for (int i = gtid; i < ATT_*ENC_/8; i += NT) cvt8(W_enc_att + (size_t)i*8, wencb + (size_t)i*8);
    for (int i = gtid; i < ATT_*DEC_/8; i += NT) cvt8(W_dec_att + (size_t)i*8, wdecb + (size_t)i*8);
    for (int i = gtid; i < V_*DEC_/8;   i += NT) cvt8(W_fc + (size_t)i*8, wfcb + (size_t)i*8);
    for (int i = gtid; i < G4_*XK2_/8;  i += NT) {     // wcat2: [n][ctx2048|h512]
        int n = (i*8) / XK2_, k = (i*8) % XK2_;
        const float* src = (k < ENC_) ? (W_ih + (size_t)n*KIH_ + EMB_ + k)
                                      : (W_hh + (size_t)n*DEC_ + (k - ENC_));
        cvt8(src, wcat2 + (size_t)i*8);
    }
    for (int i = gtid; i < G4_*EMB_/8;  i += NT)       // wembW: W_ih emb part
        cvt8(W_ih + ((size_t)((i*8) / EMB_))*KIH_ + ((i*8) % EMB_), wembW + (size_t)i*8);
    for (int i = gtid; i < 1024*ENC_/8; i += NT) {
        int n = (i*8) >> 11, k = (i*8) & (ENC_ - 1);
        const float* src = (n < 512) ? (W_init_h + (size_t)n*ENC_ + k)
                                     : (W_init_c + (size_t)(n-512)*ENC_ + k);
        cvt8(src, winitb + (size_t)i*8);
    }
    for (int i = gtid; i < T_*B_*EMB_/8; i += NT) {    // xembA row r = t*64+b
        int r = i >> 6, c8 = i & 63;
        int t = r >> 6, b = r & 63;
        int cap = captions[b*MAXLEN_ + t];
        cvt8(emb_table + (size_t)cap*EMB_ + c8*8, xembA + (size_t)r*EMB_ + c8*8);
    }
    if (gtid < G4_) bsum[gtid] = b_ih[gtid] + b_hh[gtid];
    if (gtid < B_*ENC_) {
        int b = gtid >> 11, e = gtid & (ENC_ - 1);
        const float* base = enc + (size_t)b*P_*ENC_ + e;
        float s = 0.f;
        for (int p = 0; p < P_; ++p) s += base[(size_t)p*ENC_];
        meanbb[gtid] = f2bf(s * (1.f / P_));
    }
    gbar<true>(flags, ++tok);

    // ---------------- S0b: h0/c0 (256 tasks) + gpe GEMM (1856 tasks) ----------------
    for (int task = wid; task < 256 + 1856; task += NW) {
        const int r = lane & 15, g = lane >> 4;
        if (task < 256) {
            const int mt = task & 3, nt = task >> 2;
            const int m0 = mt*16, n0 = nt*16;
            const us* Ar = meanbb + (size_t)(m0 + r)*ENC_ + g*8;
            const us* Br = winitb + (size_t)(n0 + r)*ENC_ + g*8;
            f32x4 acc0 = {0,0,0,0}, acc1 = {0,0,0,0};
#pragma unroll 4
            for (int k0 = 0; k0 < ENC_; k0 += 64) {
                acc0 = __builtin_amdgcn_mfma_f32_16x16x32_bf16(
                    *(const short8*)(Ar + k0), *(const short8*)(Br + k0), acc0, 0, 0, 0);
                acc1 = __builtin_amdgcn_mfma_f32_16x16x32_bf16(
                    *(const short8*)(Ar + k0 + 32), *(const short8*)(Br + k0 + 32), acc1, 0, 0, 0);
            }
            const int n = n0 + r;
            if (n < 512) {
                float bv = b_init_h[n];
#pragma unroll
                for (int i = 0; i < 4; ++i) {
                    int b = m0 + g*4 + i;
                    unsigned hv = f2bf(acc0[i] + acc1[i] + bv);
                    st2cc(hb1 + b*DEC_ + n, hv);
                    st2cc(xcatb + (size_t)b*XK2_ + ENC_ + n, hv);
                }
            } else {
                int d = n - 512;
                float bv = b_init_c[d];
#pragma unroll
                for (int i = 0; i < 4; ++i)
                    st4cc(cst + (m0 + g*4 + i)*DEC_ + d,
                          __float_as_uint(acc0[i] + acc1[i] + bv));
            }
        } else {
            // gpe = xembA @ wembW^T + bsum   (M=1856, N=2048, K=512), 64x32 tiles
            const int q = task - 256;
            const int m0 = (q >> 6) * 64, n0 = (q & 63) * 32;
            f32x4 acc[4][2] = {};
            const us* Ab = xembA + (size_t)(m0 + r)*EMB_ + g*8;
            const us* Bb = wembW + (size_t)(n0 + r)*EMB_ + g*8;
#pragma unroll 2
            for (int k0 = 0; k0 < EMB_; k0 += 32) {
                short8 af[4], bfr[2];
#pragma unroll
                for (int mi = 0; mi < 4; ++mi)
                    af[mi] = *(const short8*)(Ab + (size_t)mi*16*EMB_ + k0);
#pragma unroll
                for (int nj = 0; nj < 2; ++nj)
                    bfr[nj] = *(const short8*)(Bb + (size_t)nj*16*EMB_ + k0);
#pragma unroll
                for (int mi = 0; mi < 4; ++mi)
#pragma unroll
                    for (int nj = 0; nj < 2; ++nj)
                        acc[mi][nj] = __builtin_amdgcn_mfma_f32_16x16x32_bf16(
                            af[mi], bfr[nj], acc[mi][nj], 0, 0, 0);
            }
#pragma unroll
            for (int mi = 0; mi < 4; ++mi)
#pragma unroll
                for (int nj = 0; nj < 2; ++nj) {
                    int n = n0 + nj*16 + r;
                    float bv = bsum[n];
#pragma unroll
                    for (int i = 0; i < 4; ++i) {
                        int m = m0 + mi*16 + g*4 + i;
                        gpe[(size_t)m*G4_ + n] = acc[mi][nj][i] + bv;
                    }
                }
        }
    }
    gbar<true>(flags, ++tok);

    // ---------------- S0c: att1 (3136) + att2-init (128) ----------------
    for (int task = wid; task < 3264; task += NW) {
        const int r = lane & 15, g = lane >> 4;
        if (task < 3136) {
            int mt = task >> 4, nt2 = task & 15;
            int m0 = mt*64, n0 = nt2*32;
            f32x4 acc[4][2] = {};
            const us* Ab = encb + (size_t)(m0 + r)*ENC_ + g*8;
            const us* Bb = wencb + (size_t)(n0 + r)*ENC_ + g*8;
#pragma unroll 2
            for (int k0 = 0; k0 < ENC_; k0 += 32) {
                short8 af[4], bfr[2];
#pragma unroll
                for (int mi = 0; mi < 4; ++mi)
                    af[mi] = *(const short8*)(Ab + (size_t)mi*16*ENC_ + k0);
#pragma unroll
                for (int nj = 0; nj < 2; ++nj)
                    bfr[nj] = *(const short8*)(Bb + (size_t)nj*16*ENC_ + k0);
#pragma unroll
                for (int mi = 0; mi < 4; ++mi)
#pragma unroll
                    for (int nj = 0; nj < 2; ++nj)
                        acc[mi][nj] = __builtin_amdgcn_mfma_f32_16x16x32_bf16(
                            af[mi], bfr[nj], acc[mi][nj], 0, 0, 0);
            }
#pragma unroll
            for (int mi = 0; mi < 4; ++mi)
#pragma unroll
                for (int nj = 0; nj < 2; ++nj) {
                    int n = n0 + nj*16 + r;
                    float bv = b_enc_att[n];
#pragma unroll
                    for (int i = 0; i < 4; ++i) {
                        int m = m0 + mi*16 + g*4 + i;
                        att1b[(size_t)m*ATT_ + n] = f2bf(acc[mi][nj][i] + bv);
                    }
                }
        } else {
            int q = task - 3136;
            int nt = q >> 2, mt = q & 3;
            const us* Ar = hb1 + (size_t)(mt*16 + r)*DEC_ + g*8;
            const us* Br = wdecb + (size_t)(nt*16 + r)*DEC_ + g*8;
            f32x4 acc0 = {0,0,0,0}, acc1 = {0,0,0,0};
#pragma unroll 4
            for (int k0 = 0; k0 < DEC_; k0 += 64) {
                short8 a0, a1, dum;
                ld16cc_x3(Ar + k0, Ar + k0 + 32, Ar + k0, &a0, &a1, &dum);
                acc0 = __builtin_amdgcn_mfma_f32_16x16x32_bf16(
                    a0, *(const short8*)(Br + k0), acc0, 0, 0, 0);
                acc1 = __builtin_amdgcn_mfma_f32_16x16x32_bf16(
                    a1, *(const short8*)(Br + k0 + 32), acc1, 0, 0, 0);
            }
            int n = nt*16 + r;
            float bv = b_dec_att[n];
#pragma unroll
            for (int i = 0; i < 4; ++i)
                st4cc(att2G + (size_t)(mt*16 + g*4 + i)*ATT_ + n,
                      __float_as_uint(acc0[i] + acc1[i] + bv));
        }
    }
    gbar<true>(flags, ++tok);

    // ---- pre-loop: persistent weight staging + creg load -------------------
    {
        const int z = bid >> 5, nb = bid & 31;
        for (int c = tid; c < 2560; c += TPB) {
            int row = c / 40, col8 = c % 40;
            *(short8*)(s_wb + row*328 + col8*8) =
                *(const short8*)(wcat2 + (size_t)(nb*64 + row)*XK2_ + (size_t)z*320 + col8*8);
        }
        if (bid < 32)
            for (int c = tid; c < 1024; c += TPB) {
                int row = c >> 6, col8 = c & 63;
                *(short8*)(s_wd + row*520 + col8*8) =
                    *(const short8*)(wdecb + (size_t)(bid*16 + row)*DEC_ + col8*8);
            }
        if (tid < 128) creg = __uint_as_float(ld4cc(cst + bid*128 + tid));
        __syncthreads();
    }
    // loop-invariant score weights
    const float4 w0v = *(const float4*)(w_full + lane*8);
    const float4 w1v = *(const float4*)(w_full + lane*8 + 4);

    // ================= decode loop: 3 barriers + att2 flag wait =================
    for (int t = 0; t < T_; ++t) {
        // ---- E: wait att2(t-1) flags; scores (batched loads) + softmax + ctx ----
        {
            if (t > 0) {
                if (tid < 32) {
                    while (__hip_atomic_load(&aflags[tid * FSTR], __ATOMIC_RELAXED,
                                             __HIP_MEMORY_SCOPE_AGENT) < (unsigned)t)
                        __builtin_amdgcn_s_sleep(1);
                }
                __syncthreads();
            }
            const int b = bid & 63, cc = bid >> 6;
            f32x4 a2lo, a2hi;
            const float* ap = att2G + (size_t)b*ATT_ + lane*8;
            ldf8cc(ap, ap + 4, &a2lo, &a2hi);
            const us* a1base = att1b + (size_t)b*P_*ATT_ + lane*8;
            // rows p = w + 16j, j = 0..12 (j=12 valid only for w<4): 2 load batches
            const bool v12 = (w + 192) < P_;
            {
                short8 sv[7];
                float sc[13];
                ldg7(a1base + (size_t)(w      )*ATT_, a1base + (size_t)(w +  16)*ATT_,
                     a1base + (size_t)(w +  32)*ATT_, a1base + (size_t)(w +  48)*ATT_,
                     a1base + (size_t)(w +  64)*ATT_, a1base + (size_t)(w +  80)*ATT_,
                     a1base + (size_t)(w +  96)*ATT_, sv);
#pragma unroll
                for (int j = 0; j < 7; ++j)
                    sc[j] = wredsum(score8(sv[j], a2lo, a2hi, w0v, w1v));
                ldg6(a1base + (size_t)(w + 112)*ATT_, a1base + (size_t)(w + 128)*ATT_,
                     a1base + (size_t)(w + 144)*ATT_, a1base + (size_t)(w + 160)*ATT_,
                     a1base + (size_t)(w + 176)*ATT_,
                     v12 ? a1base + (size_t)(w + 192)*ATT_ : a1base, sv);
#pragma unroll
                for (int j = 0; j < 6; ++j)
                    sc[7 + j] = wredsum(score8(sv[j], a2lo, a2hi, w0v, w1v));
                if (lane == 0) {
#pragma unroll
                    for (int j = 0; j < 12; ++j) s_e[w + 16*j] = sc[j];
                    if (v12) s_e[w + 192] = sc[12];
                }
            }
            __syncthreads();
            float v = (tid < P_) ? s_e[tid] : -3.4e38f;
            float mx = v;
#pragma unroll
            for (int o = 32; o > 0; o >>= 1) mx = fmaxf(mx, __shfl_xor(mx, o));
            if (lane == 0) s_red[w] = mx;
            __syncthreads();
            mx = s_red[0];
#pragma unroll
            for (int j = 1; j < 16; ++j) mx = fmaxf(mx, s_red[j]);
            float ev = (tid < P_) ? expf(v - mx) : 0.f;
            float sm = wredsum(ev);
            if (lane == 0) s_red[16 + w] = sm;
            __syncthreads();
            float tot = 0.f;
#pragma unroll
            for (int j = 0; j < 16; ++j) tot += s_red[16 + j];
            if (tid < P_) {
                float al = ev / tot;
                s_al[tid] = al;
                if (cc == 0) outa[((size_t)b*T_ + t)*P_ + tid] = al;
            }
            __syncthreads();
            // ctx: rows p = w + 16j, cols cc*512 + lane*8, batched loads
            float a[8] = {};
            const us* ep = encb + (size_t)b*P_*ENC_ + cc*512 + lane*8;
            {
                short8 cv[7];
                ldg7(ep + (size_t)(w      )*ENC_, ep + (size_t)(w +  16)*ENC_,
                     ep + (size_t)(w +  32)*ENC_, ep + (size_t)(w +  48)*ENC_,
                     ep + (size_t)(w +  64)*ENC_, ep + (size_t)(w +  80)*ENC_,
                     ep + (size_t)(w +  96)*ENC_, cv);
#pragma unroll
                for (int j = 0; j < 7; ++j) {
                    const float al = s_al[w + 16*j];
#pragma unroll
                    for (int k = 0; k < 8; ++k) a[k] += al * bf2f((us)cv[j][k]);
                }
                ldg6(ep + (size_t)(w + 112)*ENC_, ep + (size_t)(w + 128)*ENC_,
                     ep + (size_t)(w + 144)*ENC_, ep + (size_t)(w + 160)*ENC_,
                     ep + (size_t)(w + 176)*ENC_,
                     v12 ? ep + (size_t)(w + 192)*ENC_ : ep, cv);
#pragma unroll
                for (int j = 0; j < 5; ++j) {
                    const float al = s_al[w + 112 + 16*j];
#pragma unroll
                    for (int k = 0; k < 8; ++k) a[k] += al * bf2f((us)cv[j][k]);
                }
                if (v12) {
                    const float al = s_al[w + 192];
#pragma unroll
                    for (int k = 0; k < 8; ++k) a[k] += al * bf2f((us)cv[5][k]);
                }
            }
            float* s_accf = (float*)s_stage;   // 16 x 512 fold buffer
            {
                f32x4 lo = {a[0],a[1],a[2],a[3]}, hi = {a[4],a[5],a[6],a[7]};
                *(f32x4*)(s_accf + w*512 + lane*8)     = lo;
                *(f32x4*)(s_accf + w*512 + lane*8 + 4) = hi;
            }
            __syncthreads();
            if (tid < 256) {
                int c2 = tid*2;
                float s0 = 0.f, s1 = 0.f;
#pragma unroll
                for (int q = 0; q < 16; ++q) {
                    s0 += s_accf[q*512 + c2];
                    s1 += s_accf[q*512 + c2 + 1];
                }
                unsigned pk = (unsigned)f2bf(s0) | ((unsigned)f2bf(s1) << 16);
                st4cc(xcatb + (size_t)b*XK2_ + cc*512 + c2, pk);
            }
            __syncthreads();
        }
        gbar<false>(flags, ++tok);

        // ---- B: gates split-K=8 (320/z). xcat slice -> LDS; weights LDS-resident ----
        {
            const int z = bid >> 5;
            {
                short8 v0, v1, v2;
                int c0 = tid, c1 = tid + 1024, c2i = tid + 2048;
                const us* p0 = xcatb + (size_t)(c0/40)*XK2_ + z*320 + (c0%40)*8;
                const us* p1 = xcatb + (size_t)(c1/40)*XK2_ + z*320 + (c1%40)*8;
                bool has2 = c2i < 2560;
                const us* p2 = has2 ? xcatb + (size_t)(c2i/40)*XK2_ + z*320 + (c2i%40)*8 : p0;
                ld16cc_x3(p0, p1, p2, &v0, &v1, &v2);
                *(short8*)(s_stage + (c0/40)*328 + (c0%40)*8) = v0;
                *(short8*)(s_stage + (c1/40)*328 + (c1%40)*8) = v1;
                if (has2) *(short8*)(s_stage + (c2i/40)*328 + (c2i%40)*8) = v2;
            }
            __syncthreads();
            const int nt = (bid & 31)*4 + (w >> 2), mt = w & 3;
            const int r = lane & 15, g = lane >> 4;
            const us* sxr = s_stage + (mt*16 + r)*328 + g*8;
            const us* Br  = s_wb + ((w >> 2)*16 + r)*328 + g*8;
            f32x4 acc0 = {0,0,0,0}, acc1 = {0,0,0,0};
#pragma unroll
            for (int k0 = 0; k0 < 320; k0 += 64) {
                acc0 = __builtin_amdgcn_mfma_f32_16x16x32_bf16(
                    *(const short8*)(sxr + k0), *(const short8*)(Br + k0), acc0, 0, 0, 0);
                acc1 = __builtin_amdgcn_mfma_f32_16x16x32_bf16(
                    *(const short8*)(sxr + k0 + 32), *(const short8*)(Br + k0 + 32), acc1, 0, 0, 0);
            }
            const int n = nt*16 + r;
#pragma unroll
            for (int i = 0; i < 4; ++i) {
                int m = mt*16 + g*4 + i;
                st4cc(gp + ZS_*z + (size_t)m*G4_ + n, __float_as_uint(acc0[i] + acc1[i]));
            }
            __syncthreads();
        }
        gbar<false>(flags, ++tok);

        // ---- C: LSTM. z-reduce via 512 threads -> LDS; c-state in registers ----
        {
            float* sg = (float*)s_stage;        // [4 gates][128 cells]
            if (tid < 512) {
                const int cell = tid & 127, gate = tid >> 7;
                const int idx = bid*128 + cell;
                const int b = idx >> 9, d = idx & 511;
                const float* gz = gp + (size_t)b*G4_ + gate*512 + d;
                float vz[8];
                ld4cc_x8(gz, gz + ZS_, gz + 2*ZS_, gz + 3*ZS_,
                         gz + 4*ZS_, gz + 5*ZS_, gz + 6*ZS_, gz + 7*ZS_, vz);
                sg[tid] = ((vz[0]+vz[1]) + (vz[2]+vz[3])) + ((vz[4]+vz[5]) + (vz[6]+vz[7]));
            }
            __syncthreads();
            if (tid < 128) {
                const int idx = bid*128 + tid;
                const int b = idx >> 9, d = idx & 511;
                const float* ge = gpe + ((size_t)(t*B_ + b))*G4_ + d;
                float gi = sg[tid]       + ge[0];
                float gf = sg[128 + tid] + ge[512];
                float gg = sg[256 + tid] + ge[1024];
                float go = sg[384 + tid] + ge[1536];
                float si = 1.f / (1.f + expf(-gi));
                float sf = 1.f / (1.f + expf(-gf));
                float so = 1.f / (1.f + expf(-go));
                float cn = sf * creg + si * tanhf(gg);
                creg = cn;
                float hn = so * tanhf(cn);
                unsigned hv = f2bf(hn);
                us* hnew = (t & 1) ? hb1 : hb0;
                st2cc(hnew + idx, hv);
                st2cc(xcatb + (size_t)b*XK2_ + ENC_ + d, hv);
            }
        }
        gbar<false>(flags, ++tok);

        // ---- post-C: att2(t) producers (bid<32, flag publish); preds(t-1)
        //      on bid>=32, fully unsynchronized ----
        if (bid < 32) {
            if (t != T_ - 1) {
                const us* hbn = (t & 1) ? hb1 : hb0;
                short8 v0, v1, v2, v3;
                int c0 = tid, c1 = tid + 1024, c2i = tid + 2048, c3 = tid + 3072;
                ld16cc_x4(hbn + (c0>>6)*DEC_ + (c0&63)*8, hbn + (c1>>6)*DEC_ + (c1&63)*8,
                          hbn + (c2i>>6)*DEC_ + (c2i&63)*8, hbn + (c3>>6)*DEC_ + (c3&63)*8,
                          &v0, &v1, &v2, &v3);
                *(short8*)(s_stage + (c0>>6)*520 + (c0&63)*8) = v0;
                *(short8*)(s_stage + (c1>>6)*520 + (c1&63)*8) = v1;
                *(short8*)(s_stage + (c2i>>6)*520 + (c2i&63)*8) = v2;
                *(short8*)(s_stage + (c3>>6)*520 + (c3&63)*8) = v3;
                __syncthreads();
                if (w < 4) {
                    const int r = lane & 15, g = lane >> 4;
                    const us* As = s_stage + (w*16 + r)*520 + g*8;
                    const us* Bs = s_wd + r*520 + g*8;
                    f32x4 acc0 = {0,0,0,0}, acc1 = {0,0,0,0};
#pragma unroll
                    for (int k0 = 0; k0 < DEC_; k0 += 64) {
                        acc0 = __builtin_amdgcn_mfma_f32_16x16x32_bf16(
                            *(const short8*)(As + k0), *(const short8*)(Bs + k0), acc0, 0, 0, 0);
                        acc1 = __builtin_amdgcn_mfma_f32_16x16x32_bf16(
                            *(const short8*)(As + k0 + 32), *(const short8*)(Bs + k0 + 32), acc1, 0, 0, 0);
                    }
                    const int n = bid*16 + r;
                    float bv = b_dec_att[n];
#pragma unroll
                    for (int i = 0; i < 4; ++i)
                        st4cc(att2G + (size_t)(w*16 + g*4 + i)*ATT_ + n,
                              __float_as_uint(acc0[i] + acc1[i] + bv));
                }
                asm volatile("s_waitcnt vmcnt(0)" ::: "memory");
                __syncthreads();
                if (tid == 0)
                    __hip_atomic_store(&aflags[bid * FSTR], (unsigned)(t + 1),
                                       __ATOMIC_RELAXED, __HIP_MEMORY_SCOPE_AGENT);
            }
        } else if (t > 0) {
            // preds(t-1): consumer is global output only, no sync needed
            const us* hbo = (t & 1) ? hb0 : hb1;   // h(t-1), stable
            short8 v0, v1, v2, v3;
            int c0 = tid, c1 = tid + 1024, c2i = tid + 2048, c3 = tid + 3072;
            ld16cc_x4(hbo + (c0>>6)*DEC_ + (c0&63)*8, hbo + (c1>>6)*DEC_ + (c1&63)*8,
                      hbo + (c2i>>6)*DEC_ + (c2i&63)*8, hbo + (c3>>6)*DEC_ + (c3&63)*8,
                      &v0, &v1, &v2, &v3);
            *(short8*)(s_stage + (c0>>6)*520 + (c0&63)*8) = v0;
            *(short8*)(s_stage + (c1>>6)*520 + (c1&63)*8) = v1;
            *(short8*)(s_stage + (c2i>>6)*520 + (c2i&63)*8) = v2;
            *(short8*)(s_stage + (c3>>6)*520 + (c3&63)*8) = v3;
            __syncthreads();
            const int tq = (bid - 32)*3 + w;
            if (w < 3 && tq < NPT)
                preds_task(s_stage, wfcb, b_fc, outp, tq, t - 1, lane);
            __syncthreads();
        }
    }

    // ---- tail: preds(T-1), 16 tasks/block on blocks 0..39 (no barrier) ----
    if (bid < 40) {
        __syncthreads();
        const us* hbn = ((T_ - 1) & 1) ? hb1 : hb0;
        {
            short8 v0, v1, v2, v3;
            int c0 = tid, c1 = tid + 1024, c2i = tid + 2048, c3 = tid + 3072;
            ld16cc_x4(hbn + (c0>>6)*DEC_ + (c0&63)*8, hbn + (c1>>6)*DEC_ + (c1&63)*8,
                      hbn + (c2i>>6)*DEC_ + (c2i&63)*8, hbn + (c3>>6)*DEC_ + (c3&63)*8,
                      &v0, &v1, &v2, &v3);
            *(short8*)(s_stage + (c0>>6)*520 + (c0&63)*8) = v0;
            *(short8*)(s_stage + (c1>>6)*520 + (c1&63)*8) = v1;
            *(short8*)(s_stage + (c2i>>6)*520 + (c2i&63)*8) = v2;
            *(short8*)(s_stage + (c3>>6)*520 + (c3&63)*8) = v3;
        }
        __syncthreads();
        const int tq = bid*16 + w;
        if (tq < NPT)
            preds_task(s_stage, wfcb, b_fc, outp, tq, T_ - 1, lane);
    }
}

// ---------------------------------------------------------------------------
extern "C" void kernel_launch(void* const* d_in, const int* in_sizes, int n_in,
                              void* d_out, int out_size, void* d_ws, size_t ws_size,
                              hipStream_t stream) {
    const float* enc       = (const float*)d_in[0];
    const int*   captions  = (const int*)d_in[1];
    const float* emb_table = (const float*)d_in[3];
    const float* W_enc_att = (const float*)d_in[4];
    const float* b_enc_att = (const float*)d_in[5];
    const float* W_dec_att = (const float*)d_in[6];
    const float* b_dec_att = (const float*)d_in[7];
    const float* w_full    = (const float*)d_in[8];
    const float* W_ih      = (const float*)d_in[10];
    const float* b_ih      = (const float*)d_in[11];
    const float* W_hh      = (const float*)d_in[12];
    const float* b_hh      = (const float*)d_in[13];
    const float* W_init_h  = (const float*)d_in[14];
    const float* b_init_h  = (const float*)d_in[15];
    const float* W_init_c  = (const float*)d_in[16];
    const float* b_init_c  = (const float*)d_in[17];
    const float* W_fc      = (const float*)d_in[18];
    const float* b_fc      = (const float*)d_in[19];

    char* ws = (char*)d_ws;
    size_t off = 0;
    auto alloc = [&](size_t bytes) {
        void* p = ws + off;
        off = (off + bytes + 255) & ~(size_t)255;
        return p;
    };
    us* encb   = (us*)alloc((size_t)B_ * P_ * ENC_ * 2);
    us* wencb  = (us*)alloc((size_t)ATT_ * ENC_ * 2);
    us* wdecb  = (us*)alloc((size_t)ATT_ * DEC_ * 2);
    us* wfcb   = (us*)alloc((size_t)V_ * DEC_ * 2);
    us* wcat2  = (us*)alloc((size_t)G4_ * XK2_ * 2);
    us* wembW  = (us*)alloc((size_t)G4_ * EMB_ * 2);
    us* winitb = (us*)alloc((size_t)1024 * ENC_ * 2);
    us* xembA  = (us*)alloc((size_t)T_ * B_ * EMB_ * 2);
    us* att1b  = (us*)alloc((size_t)B_ * P_ * ATT_ * 2);
    us* hbuf   = (us*)alloc((size_t)2 * B_ * DEC_ * 2);   // double-buffered h
    us* xcatb  = (us*)alloc((size_t)B_ * XK2_ * 2);
    us* meanbb = (us*)alloc((size_t)B_ * ENC_ * 2);
    float* cst   = (float*)alloc((size_t)B_ * DEC_ * 4);
    float* att2G = (float*)alloc((size_t)B_ * ATT_ * 4);
    float* gp    = (float*)alloc((size_t)B_ * G4_ * 8 * 4);
    float* gpe   = (float*)alloc((size_t)T_ * B_ * G4_ * 4);
    float* bsum  = (float*)alloc((size_t)G4_ * 4);
    unsigned* flags = (unsigned*)alloc((size_t)(NBLK + 64) * FSTR * 4);

    float* outp = (float*)d_out;
    float* outa = outp + (size_t)B_ * T_ * V_;

    hipMemsetAsync(flags, 0, (NBLK + 64) * FSTR * sizeof(unsigned), stream);
    k_persist<<<NBLK, TPB, 0, stream>>>(
        enc, captions, emb_table, W_enc_att, b_enc_att, W_dec_att, b_dec_att,
        w_full, W_ih, b_ih, W_hh, b_hh, W_init_h, b_init_h, W_init_c, b_init_c,
        W_fc, b_fc,
        encb, wencb, wdecb, wfcb, wcat2, wembW, winitb, xembA, att1b, hbuf, xcatb,
        meanbb, cst, att2G, gp, gpe, bsum, flags, outp, outa);
}

// Round 12
// 1553.338 us; speedup vs baseline: 1.0701x; 1.0701x over previous
//
#include <hip/hip_runtime.h>
#include <cstddef>

constexpr int B_   = 64;
constexpr int P_   = 196;
constexpr int ENC_ = 2048;
constexpr int ATT_ = 512;
constexpr int DEC_ = 512;
constexpr int EMB_ = 512;
constexpr int V_   = 10000;
constexpr int MAXLEN_ = 30;
constexpr int T_   = 29;
constexpr int G4_  = 2048;
constexpr int KIH_ = 2560;          // W_ih row length (emb|ctx)
constexpr int XK2_ = 2560;          // loop xcat: ctx(2048) | h(512)

constexpr int NBLK = 256;
constexpr int TPB  = 1024;
constexpr int NT   = NBLK * TPB;
constexpr int NW   = NT / 64;       // 4096 waves
constexpr int FSTR = 16;            // flag stride (dwords) = 64B
constexpr size_t ZS_ = (size_t)B_ * G4_;   // one z-slice of gp (floats)
constexpr int NPT = 625;            // preds tasks (10000/16)

typedef __attribute__((ext_vector_type(8))) short short8;
typedef __attribute__((ext_vector_type(4))) float f32x4;
using us = unsigned short;

typedef __attribute__((address_space(1))) const unsigned int guint;
typedef __attribute__((address_space(3))) unsigned int luint;

__device__ __forceinline__ us f2bf(float x) {
    union { float f; unsigned u; } v; v.f = x;
    unsigned r = v.u + 0x7fff + ((v.u >> 16) & 1);
    return (us)(r >> 16);
}
__device__ __forceinline__ float bf2f(us u) {
    union { unsigned u; float f; } v; v.u = ((unsigned)u) << 16;
    return v.f;
}

// async global->LDS, 16B per lane; LDS dest = uniform base + lane*16
__device__ __forceinline__ void gl_lds16(const us* g, us* l) {
    __builtin_amdgcn_global_load_lds((guint*)g, (luint*)l, 16, 0, 0);
}

// ---- agent-scope (sc1) L2-bypassing access helpers -------------------------
__device__ __forceinline__ unsigned ld4cc(const void* p) {
    unsigned r;
    asm volatile("global_load_dword %0, %1, off sc1\n\ts_waitcnt vmcnt(0)"
                 : "=v"(r) : "v"(p) : "memory");
    return r;
}
__device__ __forceinline__ void ld4cc_x8(const float* p0, const float* p1,
                                         const float* p2, const float* p3,
                                         const float* p4, const float* p5,
                                         const float* p6, const float* p7,
                                         float* o) {
    float r0, r1, r2, r3, r4, r5, r6, r7;
    asm volatile("global_load_dword %0, %8, off sc1\n\t"
                 "global_load_dword %1, %9, off sc1\n\t"
                 "global_load_dword %2, %10, off sc1\n\t"
                 "global_load_dword %3, %11, off sc1\n\t"
                 "global_load_dword %4, %12, off sc1\n\t"
                 "global_load_dword %5, %13, off sc1\n\t"
                 "global_load_dword %6, %14, off sc1\n\t"
                 "global_load_dword %7, %15, off sc1\n\t"
                 "s_waitcnt vmcnt(0)"
                 : "=&v"(r0), "=&v"(r1), "=&v"(r2), "=&v"(r3),
                   "=&v"(r4), "=&v"(r5), "=&v"(r6), "=&v"(r7)
                 : "v"(p0), "v"(p1), "v"(p2), "v"(p3),
                   "v"(p4), "v"(p5), "v"(p6), "v"(p7) : "memory");
    o[0]=r0; o[1]=r1; o[2]=r2; o[3]=r3; o[4]=r4; o[5]=r5; o[6]=r6; o[7]=r7;
}
__device__ __forceinline__ void ld16cc_x3(const void* p0, const void* p1, const void* p2,
                                          short8* a, short8* b, short8* c) {
    short8 ra, rb, rc;
    asm volatile("global_load_dwordx4 %0, %3, off sc1\n\t"
                 "global_load_dwordx4 %1, %4, off sc1\n\t"
                 "global_load_dwordx4 %2, %5, off sc1\n\t"
                 "s_waitcnt vmcnt(0)"
                 : "=&v"(ra), "=&v"(rb), "=&v"(rc)
                 : "v"(p0), "v"(p1), "v"(p2) : "memory");
    *a = ra; *b = rb; *c = rc;
}
__device__ __forceinline__ void ld16cc_x4(const void* p0, const void* p1,
                                          const void* p2, const void* p3,
                                          short8* a, short8* b, short8* c, short8* d) {
    short8 ra, rb, rc, rd;
    asm volatile("global_load_dwordx4 %0, %4, off sc1\n\t"
                 "global_load_dwordx4 %1, %5, off sc1\n\t"
                 "global_load_dwordx4 %2, %6, off sc1\n\t"
                 "global_load_dwordx4 %3, %7, off sc1\n\t"
                 "s_waitcnt vmcnt(0)"
                 : "=&v"(ra), "=&v"(rb), "=&v"(rc), "=&v"(rd)
                 : "v"(p0), "v"(p1), "v"(p2), "v"(p3) : "memory");
    *a = ra; *b = rb; *c = rc; *d = rd;
}
__device__ __forceinline__ void ldf8cc(const void* p0, const void* p1, f32x4* a, f32x4* b) {
    f32x4 ra, rb;
    asm volatile("global_load_dwordx4 %0, %2, off sc1\n\t"
                 "global_load_dwordx4 %1, %3, off sc1\n\t"
                 "s_waitcnt vmcnt(0)"
                 : "=&v"(ra), "=&v"(rb) : "v"(p0), "v"(p1) : "memory");
    *a = ra; *b = rb;
}
__device__ __forceinline__ void st4cc(void* p, unsigned v) {
    asm volatile("global_store_dword %0, %1, off sc1" :: "v"(p), "v"(v) : "memory");
}
__device__ __forceinline__ void st2cc(void* p, unsigned v) {
    asm volatile("global_store_short %0, %1, off sc1" :: "v"(p), "v"(v) : "memory");
}
__device__ __forceinline__ float wredsum(float a) {
#pragma unroll
    for (int o = 32; o > 0; o >>= 1) a += __shfl_xor(a, o);
    return a;
}

// all-to-all barrier
template<bool REL>
__device__ __forceinline__ void gbar_arrive(unsigned* flags, unsigned tok) {
    asm volatile("s_waitcnt vmcnt(0)" ::: "memory");
    __syncthreads();
    if (threadIdx.x == 0)
        __hip_atomic_store(&flags[blockIdx.x * FSTR], tok,
                           REL ? __ATOMIC_RELEASE : __ATOMIC_RELAXED,
                           __HIP_MEMORY_SCOPE_AGENT);
}
__device__ __forceinline__ void gbar_wait(unsigned* flags, unsigned tok) {
    if (threadIdx.x < NBLK) {
        while (__hip_atomic_load(&flags[threadIdx.x * FSTR], __ATOMIC_RELAXED,
                                 __HIP_MEMORY_SCOPE_AGENT) < tok)
            __builtin_amdgcn_s_sleep(1);
    }
    __syncthreads();
}
template<bool REL>
__device__ __forceinline__ void gbar(unsigned* flags, unsigned tok) {
    gbar_arrive<REL>(flags, tok);
    gbar_wait(flags, tok);
}

__device__ __forceinline__ void cvt8(const float* __restrict__ src, us* __restrict__ dst) {
    const float4* p = (const float4*)src;
    float4 a = p[0], b = p[1];
    union { short8 v; us u[8]; } o;
    o.u[0] = f2bf(a.x); o.u[1] = f2bf(a.y); o.u[2] = f2bf(a.z); o.u[3] = f2bf(a.w);
    o.u[4] = f2bf(b.x); o.u[5] = f2bf(b.y); o.u[6] = f2bf(b.z); o.u[7] = f2bf(b.w);
    *(short8*)dst = o.v;
}

__device__ __forceinline__ float score8(short8 v, const f32x4& lo, const f32x4& hi,
                                        const float4& w0, const float4& w1) {
    float acc = 0.f, x;
    x = bf2f((us)v[0]) + lo[0]; acc += fmaxf(x, 0.f) * w0.x;
    x = bf2f((us)v[1]) + lo[1]; acc += fmaxf(x, 0.f) * w0.y;
    x = bf2f((us)v[2]) + lo[2]; acc += fmaxf(x, 0.f) * w0.z;
    x = bf2f((us)v[3]) + lo[3]; acc += fmaxf(x, 0.f) * w0.w;
    x = bf2f((us)v[4]) + hi[0]; acc += fmaxf(x, 0.f) * w1.x;
    x = bf2f((us)v[5]) + hi[1]; acc += fmaxf(x, 0.f) * w1.y;
    x = bf2f((us)v[6]) + hi[2]; acc += fmaxf(x, 0.f) * w1.z;
    x = bf2f((us)v[7]) + hi[3]; acc += fmaxf(x, 0.f) * w1.w;
    return acc;
}

// preds task: 64x16 output tile, A (h snapshot) from LDS, B = wfcb rows.
__device__ __forceinline__ void preds_task(const us* s_h, const us* __restrict__ wfcb,
                                           const float* __restrict__ b_fc,
                                           float* __restrict__ outp,
                                           int nt, int tt, int lane) {
    const int r = lane & 15, g = lane >> 4;
    f32x4 acc[4] = {{0,0,0,0},{0,0,0,0},{0,0,0,0},{0,0,0,0}};
    const us* Brow = wfcb + (size_t)(nt*16 + r)*DEC_ + g*8;
    const us* As   = s_h + r*520 + g*8;
#pragma unroll
    for (int k0 = 0; k0 < DEC_; k0 += 64) {
        short8 b0 = *(const short8*)(Brow + k0);
        short8 b1 = *(const short8*)(Brow + k0 + 32);
#pragma unroll
        for (int mt = 0; mt < 4; ++mt) {
            short8 a0 = *(const short8*)(As + mt*16*520 + k0);
            short8 a1 = *(const short8*)(As + mt*16*520 + k0 + 32);
            acc[mt] = __builtin_amdgcn_mfma_f32_16x16x32_bf16(a0, b0, acc[mt], 0, 0, 0);
            acc[mt] = __builtin_amdgcn_mfma_f32_16x16x32_bf16(a1, b1, acc[mt], 0, 0, 0);
        }
    }
    const int n = nt*16 + r;
    const float bv = b_fc[n];
#pragma unroll
    for (int mt = 0; mt < 4; ++mt)
#pragma unroll
        for (int i = 0; i < 4; ++i) {
            int b = mt*16 + g*4 + i;
            outp[(size_t)b*(T_*V_) + (size_t)tt*V_ + n] = acc[mt][i] + bv;
        }
}

__global__ __launch_bounds__(TPB)
void k_persist(
    const float* __restrict__ enc, const int* __restrict__ captions,
    const float* __restrict__ emb_table,
    const float* __restrict__ W_enc_att, const float* __restrict__ b_enc_att,
    const float* __restrict__ W_dec_att, const float* __restrict__ b_dec_att,
    const float* __restrict__ w_full,
    const float* __restrict__ W_ih, const float* __restrict__ b_ih,
    const float* __restrict__ W_hh, const float* __restrict__ b_hh,
    const float* __restrict__ W_init_h, const float* __restrict__ b_init_h,
    const float* __restrict__ W_init_c, const float* __restrict__ b_init_c,
    const float* __restrict__ W_fc, const float* __restrict__ b_fc,
    us* encb, us* wencb, us* wdecb, us* wfcb, us* wcat2, us* wembW,
    us* winitb, us* xembA, us* att1b, us* hbuf, us* xcatb, us* meanbb,
    float* cst, float* att2G, float* gp, float* gpe, float* bsum,
    unsigned* flags, float* outp, float* outa)
{
    __shared__ us s_stage[64 * 520];          // staging / fold / DMA dbuf (66.5 KB)
    __shared__ us s_wb[64 * 328];             // persistent wcat2 slice (41 KB)
    __shared__ us s_wd[16 * 520];             // persistent wdec slice (16.6 KB, bid<32)
    __shared__ float s_e[P_];
    __shared__ float s_al[P_];
    __shared__ float s_red[32];

    const int tid = threadIdx.x, bid = blockIdx.x;
    const int gtid = bid * TPB + tid;
    const int wid  = gtid >> 6;
    const int w    = tid >> 6;
    const int lane = tid & 63;
    unsigned tok = 0;
    float creg = 0.f;                          // persistent LSTM cell state
    us* const hb0 = hbuf;                      // h(t) for even t
    us* const hb1 = hbuf + (size_t)B_ * DEC_;  // h(t) for odd t; h0 lives here
    unsigned* const aflags = flags + (NBLK + 16) * FSTR;   // att2 producer flags (32)

    // ---------------- S0a: bf16 casts + bias-sum + mean + xembA gather ----------------
    for (int i = gtid; i < B_*P_*ENC_/8; i += NT) cvt8(enc + (size_t)i*8, encb + (size_t)i*8);
    for (int i = gtid; i < ATT_*ENC_/8; i += NT) cvt8(W_enc_att + (size_t)i*8, wencb + (size_t)i*8);
    for (int i = gtid; i < ATT_*DEC_/8; i += NT) cvt8(W_dec_att + (size_t)i*8, wdecb + (size_t)i*8);
    for (int i = gtid; i < V_*DEC_/8;   i += NT) cvt8(W_fc + (size_t)i*8, wfcb + (size_t)i*8);
    for (int i = gtid; i < G4_*XK2_/8;  i += NT) {     // wcat2: [n][ctx2048|h512]
        int n = (i*8) / XK2_, k = (i*8) % XK2_;
        const float* src = (k < ENC_) ? (W_ih + (size_t)n*KIH_ + EMB_ + k)
                                      : (W_hh + (size_t)n*DEC_ + (k - ENC_));
        cvt8(src, wcat2 + (size_t)i*8);
    }
    for (int i = gtid; i < G4_*EMB_/8;  i += NT)       // wembW: W_ih emb part
        cvt8(W_ih + ((size_t)((i*8) / EMB_))*KIH_ + ((i*8) % EMB_), wembW + (size_t)i*8);
    for (int i = gtid; i < 1024*ENC_/8; i += NT) {
        int n = (i*8) >> 11, k = (i*8) & (ENC_ - 1);
        const float* src = (n < 512) ? (W_init_h + (size_t)n*ENC_ + k)
                                     : (W_init_c + (size_t)(n-512)*ENC_ + k);
        cvt8(src, winitb + (size_t)i*8);
    }
    for (int i = gtid; i < T_*B_*EMB_/8; i += NT) {    // xembA row r = t*64+b
        int r = i >> 6, c8 = i & 63;
        int t = r >> 6, b = r & 63;
        int cap = captions[b*MAXLEN_ + t];
        cvt8(emb_table + (size_t)cap*EMB_ + c8*8, xembA + (size_t)r*EMB_ + c8*8);
    }
    if (gtid < G4_) bsum[gtid] = b_ih[gtid] + b_hh[gtid];
    if (gtid < B_*ENC_) {
        int b = gtid >> 11, e = gtid & (ENC_ - 1);
        const float* base = enc + (size_t)b*P_*ENC_ + e;
        float s = 0.f;
        for (int p = 0; p < P_; ++p) s += base[(size_t)p*ENC_];
        meanbb[gtid] = f2bf(s * (1.f / P_));
    }
    gbar<true>(flags, ++tok);

    // ---------------- S0b: h0/c0 (256 tasks) + gpe GEMM (1856 tasks) ----------------
    for (int task = wid; task < 256 + 1856; task += NW) {
        const int r = lane & 15, g = lane >> 4;
        if (task < 256) {
            const int mt = task & 3, nt = task >> 2;
            const int m0 = mt*16, n0 = nt*16;
            const us* Ar = meanbb + (size_t)(m0 + r)*ENC_ + g*8;
            const us* Br = winitb + (size_t)(n0 + r)*ENC_ + g*8;
            f32x4 acc0 = {0,0,0,0}, acc1 = {0,0,0,0};
#pragma unroll 4
            for (int k0 = 0; k0 < ENC_; k0 += 64) {
                acc0 = __builtin_amdgcn_mfma_f32_16x16x32_bf16(
                    *(const short8*)(Ar + k0), *(const short8*)(Br + k0), acc0, 0, 0, 0);
                acc1 = __builtin_amdgcn_mfma_f32_16x16x32_bf16(
                    *(const short8*)(Ar + k0 + 32), *(const short8*)(Br + k0 + 32), acc1, 0, 0, 0);
            }
            const int n = n0 + r;
            if (n < 512) {
                float bv = b_init_h[n];
#pragma unroll
                for (int i = 0; i < 4; ++i) {
                    int b = m0 + g*4 + i;
                    unsigned hv = f2bf(acc0[i] + acc1[i] + bv);
                    st2cc(hb1 + b*DEC_ + n, hv);
                    st2cc(xcatb + (size_t)b*XK2_ + ENC_ + n, hv);
                }
            } else {
                int d = n - 512;
                float bv = b_init_c[d];
#pragma unroll
                for (int i = 0; i < 4; ++i)
                    st4cc(cst + (m0 + g*4 + i)*DEC_ + d,
                          __float_as_uint(acc0[i] + acc1[i] + bv));
            }
        } else {
            // gpe = xembA @ wembW^T + bsum   (M=1856, N=2048, K=512), 64x32 tiles
            const int q = task - 256;
            const int m0 = (q >> 6) * 64, n0 = (q & 63) * 32;
            f32x4 acc[4][2] = {};
            const us* Ab = xembA + (size_t)(m0 + r)*EMB_ + g*8;
            const us* Bb = wembW + (size_t)(n0 + r)*EMB_ + g*8;
#pragma unroll 2
            for (int k0 = 0; k0 < EMB_; k0 += 32) {
                short8 af[4], bfr[2];
#pragma unroll
                for (int mi = 0; mi < 4; ++mi)
                    af[mi] = *(const short8*)(Ab + (size_t)mi*16*EMB_ + k0);
#pragma unroll
                for (int nj = 0; nj < 2; ++nj)
                    bfr[nj] = *(const short8*)(Bb + (size_t)nj*16*EMB_ + k0);
#pragma unroll
                for (int mi = 0; mi < 4; ++mi)
#pragma unroll
                    for (int nj = 0; nj < 2; ++nj)
                        acc[mi][nj] = __builtin_amdgcn_mfma_f32_16x16x32_bf16(
                            af[mi], bfr[nj], acc[mi][nj], 0, 0, 0);
            }
#pragma unroll
            for (int mi = 0; mi < 4; ++mi)
#pragma unroll
                for (int nj = 0; nj < 2; ++nj) {
                    int n = n0 + nj*16 + r;
                    float bv = bsum[n];
#pragma unroll
                    for (int i = 0; i < 4; ++i) {
                        int m = m0 + mi*16 + g*4 + i;
                        gpe[(size_t)m*G4_ + n] = acc[mi][nj][i] + bv;
                    }
                }
        }
    }
    gbar<true>(flags, ++tok);

    // ---------------- S0c: att1 (3136) + att2-init (128) ----------------
    for (int task = wid; task < 3264; task += NW) {
        const int r = lane & 15, g = lane >> 4;
        if (task < 3136) {
            int mt = task >> 4, nt2 = task & 15;
            int m0 = mt*64, n0 = nt2*32;
            f32x4 acc[4][2] = {};
            const us* Ab = encb + (size_t)(m0 + r)*ENC_ + g*8;
            const us* Bb = wencb + (size_t)(n0 + r)*ENC_ + g*8;
#pragma unroll 2
            for (int k0 = 0; k0 < ENC_; k0 += 32) {
                short8 af[4], bfr[2];
#pragma unroll
                for (int mi = 0; mi < 4; ++mi)
                    af[mi] = *(const short8*)(Ab + (size_t)mi*16*ENC_ + k0);
#pragma unroll
                for (int nj = 0; nj < 2; ++nj)
                    bfr[nj] = *(const short8*)(Bb + (size_t)nj*16*ENC_ + k0);
#pragma unroll
                for (int mi = 0; mi < 4; ++mi)
#pragma unroll
                    for (int nj = 0; nj < 2; ++nj)
                        acc[mi][nj] = __builtin_amdgcn_mfma_f32_16x16x32_bf16(
                            af[mi], bfr[nj], acc[mi][nj], 0, 0, 0);
            }
#pragma unroll
            for (int mi = 0; mi < 4; ++mi)
#pragma unroll
                for (int nj = 0; nj < 2; ++nj) {
                    int n = n0 + nj*16 + r;
                    float bv = b_enc_att[n];
#pragma unroll
                    for (int i = 0; i < 4; ++i) {
                        int m = m0 + mi*16 + g*4 + i;
                        att1b[(size_t)m*ATT_ + n] = f2bf(acc[mi][nj][i] + bv);
                    }
                }
        } else {
            int q = task - 3136;
            int nt = q >> 2, mt = q & 3;
            const us* Ar = hb1 + (size_t)(mt*16 + r)*DEC_ + g*8;
            const us* Br = wdecb + (size_t)(nt*16 + r)*DEC_ + g*8;
            f32x4 acc0 = {0,0,0,0}, acc1 = {0,0,0,0};
#pragma unroll 4
            for (int k0 = 0; k0 < DEC_; k0 += 64) {
                short8 a0, a1, dum;
                ld16cc_x3(Ar + k0, Ar + k0 + 32, Ar + k0, &a0, &a1, &dum);
                acc0 = __builtin_amdgcn_mfma_f32_16x16x32_bf16(
                    a0, *(const short8*)(Br + k0), acc0, 0, 0, 0);
                acc1 = __builtin_amdgcn_mfma_f32_16x16x32_bf16(
                    a1, *(const short8*)(Br + k0 + 32), acc1, 0, 0, 0);
            }
            int n = nt*16 + r;
            float bv = b_dec_att[n];
#pragma unroll
            for (int i = 0; i < 4; ++i)
                st4cc(att2G + (size_t)(mt*16 + g*4 + i)*ATT_ + n,
                      __float_as_uint(acc0[i] + acc1[i] + bv));
        }
    }
    gbar<true>(flags, ++tok);

    // ---- pre-loop: persistent weight staging + creg load -------------------
    {
        const int z = bid >> 5, nb = bid & 31;
        for (int c = tid; c < 2560; c += TPB) {
            int row = c / 40, col8 = c % 40;
            *(short8*)(s_wb + row*328 + col8*8) =
                *(const short8*)(wcat2 + (size_t)(nb*64 + row)*XK2_ + (size_t)z*320 + col8*8);
        }
        if (bid < 32)
            for (int c = tid; c < 1024; c += TPB) {
                int row = c >> 6, col8 = c & 63;
                *(short8*)(s_wd + row*520 + col8*8) =
                    *(const short8*)(wdecb + (size_t)(bid*16 + row)*DEC_ + col8*8);
            }
        if (tid < 128) creg = __uint_as_float(ld4cc(cst + bid*128 + tid));
        __syncthreads();
    }
    // loop-invariant score weights
    const float4 w0v = *(const float4*)(w_full + lane*8);
    const float4 w1v = *(const float4*)(w_full + lane*8 + 4);
    us* const sbuf0 = s_stage;            // DMA chunk buffers: 32 rows x 512 us each
    us* const sbuf1 = s_stage + 32*512;

    // ================= decode loop: 3 barriers + att2 flag wait =================
    for (int t = 0; t < T_; ++t) {
        // ---- E: scores + softmax + ctx, DMA-chunked via global_load_lds ----
        {
            if (t > 0) {
                if (tid < 32) {
                    while (__hip_atomic_load(&aflags[tid * FSTR], __ATOMIC_RELAXED,
                                             __HIP_MEMORY_SCOPE_AGENT) < (unsigned)t)
                        __builtin_amdgcn_s_sleep(1);
                }
                __syncthreads();
            }
            const int b = bid & 63, cc = bid >> 6;
            f32x4 a2lo, a2hi;
            const float* ap = att2G + (size_t)b*ATT_ + lane*8;
            ldf8cc(ap, ap + 4, &a2lo, &a2hi);
            const us* a1base = att1b + (size_t)b*P_*ATT_ + lane*8;
            const us* epb    = encb + (size_t)b*P_*ENC_ + cc*512 + lane*8;

            // ---- scores: 7 chunks (32,32,32,32,32,32,4), 2 rows per wave ----
            {
                const int rr = w*2;
                // issue chunk 0
                if (rr < 32) {
                    gl_lds16(a1base + (size_t)(rr    )*ATT_, sbuf0 + (size_t)(rr    )*512);
                    gl_lds16(a1base + (size_t)(rr + 1)*ATT_, sbuf0 + (size_t)(rr + 1)*512);
                }
                for (int c = 0; c < 7; ++c) {
                    if (c < 6) {
                        const int r0n = (c + 1)*32, nrn = (c + 1 < 6) ? 32 : 4;
                        if (rr < nrn) {
                            us* lb = ((c + 1) & 1) ? sbuf1 : sbuf0;
                            gl_lds16(a1base + (size_t)(r0n + rr    )*ATT_, lb + (size_t)(rr    )*512);
                            gl_lds16(a1base + (size_t)(r0n + rr + 1)*ATT_, lb + (size_t)(rr + 1)*512);
                        }
                    }
                    const bool in2 = (c < 5) || (c == 5 && w < 2);
                    if (in2) asm volatile("s_waitcnt vmcnt(2)" ::: "memory");
                    else     asm volatile("s_waitcnt vmcnt(0)" ::: "memory");
                    __syncthreads();
                    const int r0 = c*32, nr = (c < 6) ? 32 : 4;
                    if (rr < nr) {
                        const us* lb = (c & 1) ? sbuf1 : sbuf0;
#pragma unroll
                        for (int i = 0; i < 2; ++i) {
                            short8 v = *(const short8*)(lb + (size_t)(rr + i)*512 + lane*8);
                            float sc = wredsum(score8(v, a2lo, a2hi, w0v, w1v));
                            if (lane == 0) s_e[r0 + rr + i] = sc;
                        }
                    }
                    __syncthreads();
                }
            }
            // issue ctx chunk 0 (hides under softmax)
            {
                const int rr = w*2;
                if (rr < 32) {
                    gl_lds16(epb + (size_t)(rr    )*ENC_, sbuf0 + (size_t)(rr    )*512);
                    gl_lds16(epb + (size_t)(rr + 1)*ENC_, sbuf0 + (size_t)(rr + 1)*512);
                }
            }
            // ---- softmax (s_e -> s_al) ----
            float v = (tid < P_) ? s_e[tid] : -3.4e38f;
            float mx = v;
#pragma unroll
            for (int o = 32; o > 0; o >>= 1) mx = fmaxf(mx, __shfl_xor(mx, o));
            if (lane == 0) s_red[w] = mx;
            __syncthreads();
            mx = s_red[0];
#pragma unroll
            for (int j = 1; j < 16; ++j) mx = fmaxf(mx, s_red[j]);
            float ev = (tid < P_) ? expf(v - mx) : 0.f;
            float sm = wredsum(ev);
            if (lane == 0) s_red[16 + w] = sm;
            __syncthreads();
            float tot = 0.f;
#pragma unroll
            for (int j = 0; j < 16; ++j) tot += s_red[16 + j];
            if (tid < P_) {
                float al = ev / tot;
                s_al[tid] = al;
                if (cc == 0) outa[((size_t)b*T_ + t)*P_ + tid] = al;
            }
            __syncthreads();

            // ---- ctx: 7 chunks, accumulate a[8] per (w,lane) ----
            float a[8] = {};
            {
                const int rr = w*2;
                for (int c = 0; c < 7; ++c) {
                    if (c < 6) {
                        const int r0n = (c + 1)*32, nrn = (c + 1 < 6) ? 32 : 4;
                        if (rr < nrn) {
                            us* lb = ((c + 1) & 1) ? sbuf1 : sbuf0;
                            gl_lds16(epb + (size_t)(r0n + rr    )*ENC_, lb + (size_t)(rr    )*512);
                            gl_lds16(epb + (size_t)(r0n + rr + 1)*ENC_, lb + (size_t)(rr + 1)*512);
                        }
                    }
                    const bool in2 = (c < 5) || (c == 5 && w < 2);
                    if (in2) asm volatile("s_waitcnt vmcnt(2)" ::: "memory");
                    else     asm volatile("s_waitcnt vmcnt(0)" ::: "memory");
                    __syncthreads();
                    const int r0 = c*32, nr = (c < 6) ? 32 : 4;
                    if (rr < nr) {
                        const us* lb = (c & 1) ? sbuf1 : sbuf0;
#pragma unroll
                        for (int i = 0; i < 2; ++i) {
                            short8 vv = *(const short8*)(lb + (size_t)(rr + i)*512 + lane*8);
                            const float al = s_al[r0 + rr + i];
#pragma unroll
                            for (int k = 0; k < 8; ++k) a[k] += al * bf2f((us)vv[k]);
                        }
                    }
                    __syncthreads();
                }
            }
            float* s_accf = (float*)s_stage;   // 16 x 512 fold buffer
            {
                f32x4 lo = {a[0],a[1],a[2],a[3]}, hi = {a[4],a[5],a[6],a[7]};
                *(f32x4*)(s_accf + w*512 + lane*8)     = lo;
                *(f32x4*)(s_accf + w*512 + lane*8 + 4) = hi;
            }
            __syncthreads();
            if (tid < 256) {
                int c2 = tid*2;
                float s0 = 0.f, s1 = 0.f;
#pragma unroll
                for (int q = 0; q < 16; ++q) {
                    s0 += s_accf[q*512 + c2];
                    s1 += s_accf[q*512 + c2 + 1];
                }
                unsigned pk = (unsigned)f2bf(s0) | ((unsigned)f2bf(s1) << 16);
                st4cc(xcatb + (size_t)b*XK2_ + cc*512 + c2, pk);
            }
            __syncthreads();
        }
        gbar<false>(flags, ++tok);

        // ---- B: gates split-K=8 (320/z). xcat slice -> LDS; weights LDS-resident ----
        {
            const int z = bid >> 5;
            {
                short8 v0, v1, v2;
                int c0 = tid, c1 = tid + 1024, c2i = tid + 2048;
                const us* p0 = xcatb + (size_t)(c0/40)*XK2_ + z*320 + (c0%40)*8;
                const us* p1 = xcatb + (size_t)(c1/40)*XK2_ + z*320 + (c1%40)*8;
                bool has2 = c2i < 2560;
                const us* p2 = has2 ? xcatb + (size_t)(c2i/40)*XK2_ + z*320 + (c2i%40)*8 : p0;
                ld16cc_x3(p0, p1, p2, &v0, &v1, &v2);
                *(short8*)(s_stage + (c0/40)*328 + (c0%40)*8) = v0;
                *(short8*)(s_stage + (c1/40)*328 + (c1%40)*8) = v1;
                if (has2) *(short8*)(s_stage + (c2i/40)*328 + (c2i%40)*8) = v2;
            }
            __syncthreads();
            const int nt = (bid & 31)*4 + (w >> 2), mt = w & 3;
            const int r = lane & 15, g = lane >> 4;
            const us* sxr = s_stage + (mt*16 + r)*328 + g*8;
            const us* Br  = s_wb + ((w >> 2)*16 + r)*328 + g*8;
            f32x4 acc0 = {0,0,0,0}, acc1 = {0,0,0,0};
#pragma unroll
            for (int k0 = 0; k0 < 320; k0 += 64) {
                acc0 = __builtin_amdgcn_mfma_f32_16x16x32_bf16(
                    *(const short8*)(sxr + k0), *(const short8*)(Br + k0), acc0, 0, 0, 0);
                acc1 = __builtin_amdgcn_mfma_f32_16x16x32_bf16(
                    *(const short8*)(sxr + k0 + 32), *(const short8*)(Br + k0 + 32), acc1, 0, 0, 0);
            }
            const int n = nt*16 + r;
#pragma unroll
            for (int i = 0; i < 4; ++i) {
                int m = mt*16 + g*4 + i;
                st4cc(gp + ZS_*z + (size_t)m*G4_ + n, __float_as_uint(acc0[i] + acc1[i]));
            }
            __syncthreads();
        }
        gbar<false>(flags, ++tok);

        // ---- C: LSTM. z-reduce via 512 threads -> LDS; c-state in registers ----
        {
            float* sg = (float*)s_stage;        // [4 gates][128 cells]
            if (tid < 512) {
                const int cell = tid & 127, gate = tid >> 7;
                const int idx = bid*128 + cell;
                const int b = idx >> 9, d = idx & 511;
                const float* gz = gp + (size_t)b*G4_ + gate*512 + d;
                float vz[8];
                ld4cc_x8(gz, gz + ZS_, gz + 2*ZS_, gz + 3*ZS_,
                         gz + 4*ZS_, gz + 5*ZS_, gz + 6*ZS_, gz + 7*ZS_, vz);
                sg[tid] = ((vz[0]+vz[1]) + (vz[2]+vz[3])) + ((vz[4]+vz[5]) + (vz[6]+vz[7]));
            }
            __syncthreads();
            if (tid < 128) {
                const int idx = bid*128 + tid;
                const int b = idx >> 9, d = idx & 511;
                const float* ge = gpe + ((size_t)(t*B_ + b))*G4_ + d;
                float gi = sg[tid]       + ge[0];
                float gf = sg[128 + tid] + ge[512];
                float gg = sg[256 + tid] + ge[1024];
                float go = sg[384 + tid] + ge[1536];
                float si = 1.f / (1.f + expf(-gi));
                float sf = 1.f / (1.f + expf(-gf));
                float so = 1.f / (1.f + expf(-go));
                float cn = sf * creg + si * tanhf(gg);
                creg = cn;
                float hn = so * tanhf(cn);
                unsigned hv = f2bf(hn);
                us* hnew = (t & 1) ? hb1 : hb0;
                st2cc(hnew + idx, hv);
                st2cc(xcatb + (size_t)b*XK2_ + ENC_ + d, hv);
            }
        }
        gbar<false>(flags, ++tok);

        // ---- post-C: att2(t) producers (bid<32, flag publish); preds(t-1)
        //      on bid>=32, fully unsynchronized ----
        if (bid < 32) {
            if (t != T_ - 1) {
                const us* hbn = (t & 1) ? hb1 : hb0;
                short8 v0, v1, v2, v3;
                int c0 = tid, c1 = tid + 1024, c2i = tid + 2048, c3 = tid + 3072;
                ld16cc_x4(hbn + (c0>>6)*DEC_ + (c0&63)*8, hbn + (c1>>6)*DEC_ + (c1&63)*8,
                          hbn + (c2i>>6)*DEC_ + (c2i&63)*8, hbn + (c3>>6)*DEC_ + (c3&63)*8,
                          &v0, &v1, &v2, &v3);
                *(short8*)(s_stage + (c0>>6)*520 + (c0&63)*8) = v0;
                *(short8*)(s_stage + (c1>>6)*520 + (c1&63)*8) = v1;
                *(short8*)(s_stage + (c2i>>6)*520 + (c2i&63)*8) = v2;
                *(short8*)(s_stage + (c3>>6)*520 + (c3&63)*8) = v3;
                __syncthreads();
                if (w < 4) {
                    const int r = lane & 15, g = lane >> 4;
                    const us* As = s_stage + (w*16 + r)*520 + g*8;
                    const us* Bs = s_wd + r*520 + g*8;
                    f32x4 acc0 = {0,0,0,0}, acc1 = {0,0,0,0};
#pragma unroll
                    for (int k0 = 0; k0 < DEC_; k0 += 64) {
                        acc0 = __builtin_amdgcn_mfma_f32_16x16x32_bf16(
                            *(const short8*)(As + k0), *(const short8*)(Bs + k0), acc0, 0, 0, 0);
                        acc1 = __builtin_amdgcn_mfma_f32_16x16x32_bf16(
                            *(const short8*)(As + k0 + 32), *(const short8*)(Bs + k0 + 32), acc1, 0, 0, 0);
                    }
                    const int n = bid*16 + r;
                    float bv = b_dec_att[n];
#pragma unroll
                    for (int i = 0; i < 4; ++i)
                        st4cc(att2G + (size_t)(w*16 + g*4 + i)*ATT_ + n,
                              __float_as_uint(acc0[i] + acc1[i] + bv));
                }
                asm volatile("s_waitcnt vmcnt(0)" ::: "memory");
                __syncthreads();
                if (tid == 0)
                    __hip_atomic_store(&aflags[bid * FSTR], (unsigned)(t + 1),
                                       __ATOMIC_RELAXED, __HIP_MEMORY_SCOPE_AGENT);
            }
        } else if (t > 0) {
            // preds(t-1): consumer is global output only, no sync needed
            const us* hbo = (t & 1) ? hb0 : hb1;   // h(t-1), stable
            short8 v0, v1, v2, v3;
            int c0 = tid, c1 = tid + 1024, c2i = tid + 2048, c3 = tid + 3072;
            ld16cc_x4(hbo + (c0>>6)*DEC_ + (c0&63)*8, hbo + (c1>>6)*DEC_ + (c1&63)*8,
                      hbo + (c2i>>6)*DEC_ + (c2i&63)*8, hbo + (c3>>6)*DEC_ + (c3&63)*8,
                      &v0, &v1, &v2, &v3);
            *(short8*)(s_stage + (c0>>6)*520 + (c0&63)*8) = v0;
            *(short8*)(s_stage + (c1>>6)*520 + (c1&63)*8) = v1;
            *(short8*)(s_stage + (c2i>>6)*520 + (c2i&63)*8) = v2;
            *(short8*)(s_stage + (c3>>6)*520 + (c3&63)*8) = v3;
            __syncthreads();
            const int tq = (bid - 32)*3 + w;
            if (w < 3 && tq < NPT)
                preds_task(s_stage, wfcb, b_fc, outp, tq, t - 1, lane);
            __syncthreads();
        }
    }

    // ---- tail: preds(T-1), 16 tasks/block on blocks 0..39 (no barrier) ----
    if (bid < 40) {
        __syncthreads();
        const us* hbn = ((T_ - 1) & 1) ? hb1 : hb0;
        {
            short8 v0, v1, v2, v3;
            int c0 = tid, c1 = tid + 1024, c2i = tid + 2048, c3 = tid + 3072;
            ld16cc_x4(hbn + (c0>>6)*DEC_ + (c0&63)*8, hbn + (c1>>6)*DEC_ + (c1&63)*8,
                      hbn + (c2i>>6)*DEC_ + (c2i&63)*8, hbn + (c3>>6)*DEC_ + (c3&63)*8,
                      &v0, &v1, &v2, &v3);
            *(short8*)(s_stage + (c0>>6)*520 + (c0&63)*8) = v0;
            *(short8*)(s_stage + (c1>>6)*520 + (c1&63)*8) = v1;
            *(short8*)(s_stage + (c2i>>6)*520 + (c2i&63)*8) = v2;
            *(short8*)(s_stage + (c3>>6)*520 + (c3&63)*8) = v3;
        }
        __syncthreads();
        const int tq = bid*16 + w;
        if (tq < NPT)
            preds_task(s_stage, wfcb, b_fc, outp, tq, T_ - 1, lane);
    }
}

// ---------------------------------------------------------------------------
extern "C" void kernel_launch(void* const* d_in, const int* in_sizes, int n_in,
                              void* d_out, int out_size, void* d_ws, size_t ws_size,
                              hipStream_t stream) {
    const float* enc       = (const float*)d_in[0];
    const int*   captions  = (const int*)d_in[1];
    const float* emb_table = (const float*)d_in[3];
    const float* W_enc_att = (const float*)d_in[4];
    const float* b_enc_att = (const float*)d_in[5];
    const float* W_dec_att = (const float*)d_in[6];
    const float* b_dec_att = (const float*)d_in[7];
    const float* w_full    = (const float*)d_in[8];
    const float* W_ih      = (const float*)d_in[10];
    const float* b_ih      = (const float*)d_in[11];
    const float* W_hh      = (const float*)d_in[12];
    const float* b_hh      = (const float*)d_in[13];
    const float* W_init_h  = (const float*)d_in[14];
    const float* b_init_h  = (const float*)d_in[15];
    const float* W_init_c  = (const float*)d_in[16];
    const float* b_init_c  = (const float*)d_in[17];
    const float* W_fc      = (const float*)d_in[18];
    const float* b_fc      = (const float*)d_in[19];

    char* ws = (char*)d_ws;
    size_t off = 0;
    auto alloc = [&](size_t bytes) {
        void* p = ws + off;
        off = (off + bytes + 255) & ~(size_t)255;
        return p;
    };
    us* encb   = (us*)alloc((size_t)B_ * P_ * ENC_ * 2);
    us* wencb  = (us*)alloc((size_t)ATT_ * ENC_ * 2);
    us* wdecb  = (us*)alloc((size_t)ATT_ * DEC_ * 2);
    us* wfcb   = (us*)alloc((size_t)V_ * DEC_ * 2);
    us* wcat2  = (us*)alloc((size_t)G4_ * XK2_ * 2);
    us* wembW  = (us*)alloc((size_t)G4_ * EMB_ * 2);
    us* winitb = (us*)alloc((size_t)1024 * ENC_ * 2);
    us* xembA  = (us*)alloc((size_t)T_ * B_ * EMB_ * 2);
    us* att1b  = (us*)alloc((size_t)B_ * P_ * ATT_ * 2);
    us* hbuf   = (us*)alloc((size_t)2 * B_ * DEC_ * 2);   // double-buffered h
    us* xcatb  = (us*)alloc((size_t)B_ * XK2_ * 2);
    us* meanbb = (us*)alloc((size_t)B_ * ENC_ * 2);
    float* cst   = (float*)alloc((size_t)B_ * DEC_ * 4);
    float* att2G = (float*)alloc((size_t)B_ * ATT_ * 4);
    float* gp    = (float*)alloc((size_t)B_ * G4_ * 8 * 4);
    float* gpe   = (float*)alloc((size_t)T_ * B_ * G4_ * 4);
    float* bsum  = (float*)alloc((size_t)G4_ * 4);
    unsigned* flags = (unsigned*)alloc((size_t)(NBLK + 64) * FSTR * 4);

    float* outp = (float*)d_out;
    float* outa = outp + (size_t)B_ * T_ * V_;

    hipMemsetAsync(flags, 0, (NBLK + 64) * FSTR * sizeof(unsigned), stream);
    k_persist<<<NBLK, TPB, 0, stream>>>(
        enc, captions, emb_table, W_enc_att, b_enc_att, W_dec_att, b_dec_att,
        w_full, W_ih, b_ih, W_hh, b_hh, W_init_h, b_init_h, W_init_c, b_init_c,
        W_fc, b_fc,
        encb, wencb, wdecb, wfcb, wcat2, wembW, winitb, xembA, att1b, hbuf, xcatb,
        meanbb, cst, att2G, gp, gpe, bsum, flags, outp, outa);
}

// Round 13
// 1197.729 us; speedup vs baseline: 1.3878x; 1.2969x over previous
//
#include <hip/hip_runtime.h>
#include <cstddef>

constexpr int B_   = 64;
constexpr int P_   = 196;
constexpr int ENC_ = 2048;
constexpr int ATT_ = 512;
constexpr int DEC_ = 512;
constexpr int EMB_ = 512;
constexpr int V_   = 10000;
constexpr int MAXLEN_ = 30;
constexpr int T_   = 29;
constexpr int G4_  = 2048;
constexpr int KIH_ = 2560;          // W_ih row length (emb|ctx)
constexpr int XK2_ = 2560;          // loop xcat: ctx(2048) | h(512)

constexpr int NBLK = 256;
constexpr int TPB  = 1024;
constexpr int NT   = NBLK * TPB;
constexpr int NW   = NT / 64;       // 4096 waves
constexpr int FSTR = 16;            // flag stride (dwords) = 64B
constexpr size_t ZS_ = (size_t)B_ * G4_;   // one z-slice of gp (floats)
constexpr int NPT = 625;            // preds tasks (10000/16)

typedef __attribute__((ext_vector_type(8))) short short8;
typedef __attribute__((ext_vector_type(4))) float f32x4;
using us = unsigned short;

__device__ __forceinline__ us f2bf(float x) {
    union { float f; unsigned u; } v; v.f = x;
    unsigned r = v.u + 0x7fff + ((v.u >> 16) & 1);
    return (us)(r >> 16);
}
__device__ __forceinline__ float bf2f(us u) {
    union { unsigned u; float f; } v; v.u = ((unsigned)u) << 16;
    return v.f;
}

// ---- agent-scope (sc1) L2-bypassing access helpers -------------------------
__device__ __forceinline__ unsigned ld4cc(const void* p) {
    unsigned r;
    asm volatile("global_load_dword %0, %1, off sc1\n\ts_waitcnt vmcnt(0)"
                 : "=v"(r) : "v"(p) : "memory");
    return r;
}
__device__ __forceinline__ void ld4cc_x8(const float* p0, const float* p1,
                                         const float* p2, const float* p3,
                                         const float* p4, const float* p5,
                                         const float* p6, const float* p7,
                                         float* o) {
    float r0, r1, r2, r3, r4, r5, r6, r7;
    asm volatile("global_load_dword %0, %8, off sc1\n\t"
                 "global_load_dword %1, %9, off sc1\n\t"
                 "global_load_dword %2, %10, off sc1\n\t"
                 "global_load_dword %3, %11, off sc1\n\t"
                 "global_load_dword %4, %12, off sc1\n\t"
                 "global_load_dword %5, %13, off sc1\n\t"
                 "global_load_dword %6, %14, off sc1\n\t"
                 "global_load_dword %7, %15, off sc1\n\t"
                 "s_waitcnt vmcnt(0)"
                 : "=&v"(r0), "=&v"(r1), "=&v"(r2), "=&v"(r3),
                   "=&v"(r4), "=&v"(r5), "=&v"(r6), "=&v"(r7)
                 : "v"(p0), "v"(p1), "v"(p2), "v"(p3),
                   "v"(p4), "v"(p5), "v"(p6), "v"(p7) : "memory");
    o[0]=r0; o[1]=r1; o[2]=r2; o[3]=r3; o[4]=r4; o[5]=r5; o[6]=r6; o[7]=r7;
}
__device__ __forceinline__ void ld16cc_x3(const void* p0, const void* p1, const void* p2,
                                          short8* a, short8* b, short8* c) {
    short8 ra, rb, rc;
    asm volatile("global_load_dwordx4 %0, %3, off sc1\n\t"
                 "global_load_dwordx4 %1, %4, off sc1\n\t"
                 "global_load_dwordx4 %2, %5, off sc1\n\t"
                 "s_waitcnt vmcnt(0)"
                 : "=&v"(ra), "=&v"(rb), "=&v"(rc)
                 : "v"(p0), "v"(p1), "v"(p2) : "memory");
    *a = ra; *b = rb; *c = rc;
}
__device__ __forceinline__ void ld16cc_x4(const void* p0, const void* p1,
                                          const void* p2, const void* p3,
                                          short8* a, short8* b, short8* c, short8* d) {
    short8 ra, rb, rc, rd;
    asm volatile("global_load_dwordx4 %0, %4, off sc1\n\t"
                 "global_load_dwordx4 %1, %5, off sc1\n\t"
                 "global_load_dwordx4 %2, %6, off sc1\n\t"
                 "global_load_dwordx4 %3, %7, off sc1\n\t"
                 "s_waitcnt vmcnt(0)"
                 : "=&v"(ra), "=&v"(rb), "=&v"(rc), "=&v"(rd)
                 : "v"(p0), "v"(p1), "v"(p2), "v"(p3) : "memory");
    *a = ra; *b = rb; *c = rc; *d = rd;
}
__device__ __forceinline__ void ldf8cc(const void* p0, const void* p1, f32x4* a, f32x4* b) {
    f32x4 ra, rb;
    asm volatile("global_load_dwordx4 %0, %2, off sc1\n\t"
                 "global_load_dwordx4 %1, %3, off sc1\n\t"
                 "s_waitcnt vmcnt(0)"
                 : "=&v"(ra), "=&v"(rb) : "v"(p0), "v"(p1) : "memory");
    *a = ra; *b = rb;
}
__device__ __forceinline__ void st4cc(void* p, unsigned v) {
    asm volatile("global_store_dword %0, %1, off sc1" :: "v"(p), "v"(v) : "memory");
}
__device__ __forceinline__ void st2cc(void* p, unsigned v) {
    asm volatile("global_store_short %0, %1, off sc1" :: "v"(p), "v"(v) : "memory");
}
__device__ __forceinline__ float wredsum(float a) {
#pragma unroll
    for (int o = 32; o > 0; o >>= 1) a += __shfl_xor(a, o);
    return a;
}

// all-to-all barrier, split into arrive / wait.
template<bool REL>
__device__ __forceinline__ void gbar_arrive(unsigned* flags, unsigned tok) {
    asm volatile("s_waitcnt vmcnt(0)" ::: "memory");
    __syncthreads();
    if (threadIdx.x == 0)
        __hip_atomic_store(&flags[blockIdx.x * FSTR], tok,
                           REL ? __ATOMIC_RELEASE : __ATOMIC_RELAXED,
                           __HIP_MEMORY_SCOPE_AGENT);
}
__device__ __forceinline__ void gbar_wait(unsigned* flags, unsigned tok) {
    if (threadIdx.x < NBLK) {
        while (__hip_atomic_load(&flags[threadIdx.x * FSTR], __ATOMIC_RELAXED,
                                 __HIP_MEMORY_SCOPE_AGENT) < tok)
            __builtin_amdgcn_s_sleep(1);
    }
    __syncthreads();
}
template<bool REL>
__device__ __forceinline__ void gbar(unsigned* flags, unsigned tok) {
    gbar_arrive<REL>(flags, tok);
    gbar_wait(flags, tok);
}

__device__ __forceinline__ void cvt8(const float* __restrict__ src, us* __restrict__ dst) {
    const float4* p = (const float4*)src;
    float4 a = p[0], b = p[1];
    union { short8 v; us u[8]; } o;
    o.u[0] = f2bf(a.x); o.u[1] = f2bf(a.y); o.u[2] = f2bf(a.z); o.u[3] = f2bf(a.w);
    o.u[4] = f2bf(b.x); o.u[5] = f2bf(b.y); o.u[6] = f2bf(b.z); o.u[7] = f2bf(b.w);
    *(short8*)dst = o.v;
}

__device__ __forceinline__ float score8(short8 v, const f32x4& lo, const f32x4& hi,
                                        const float4& w0, const float4& w1) {
    float acc = 0.f, x;
    x = bf2f((us)v[0]) + lo[0]; acc += fmaxf(x, 0.f) * w0.x;
    x = bf2f((us)v[1]) + lo[1]; acc += fmaxf(x, 0.f) * w0.y;
    x = bf2f((us)v[2]) + lo[2]; acc += fmaxf(x, 0.f) * w0.z;
    x = bf2f((us)v[3]) + lo[3]; acc += fmaxf(x, 0.f) * w0.w;
    x = bf2f((us)v[4]) + hi[0]; acc += fmaxf(x, 0.f) * w1.x;
    x = bf2f((us)v[5]) + hi[1]; acc += fmaxf(x, 0.f) * w1.y;
    x = bf2f((us)v[6]) + hi[2]; acc += fmaxf(x, 0.f) * w1.z;
    x = bf2f((us)v[7]) + hi[3]; acc += fmaxf(x, 0.f) * w1.w;
    return acc;
}

// preds task: 64x16 output tile, A (h snapshot) from LDS, B = wfcb rows.
__device__ __forceinline__ void preds_task(const us* s_h, const us* __restrict__ wfcb,
                                           const float* __restrict__ b_fc,
                                           float* __restrict__ outp,
                                           int nt, int tt, int lane) {
    const int r = lane & 15, g = lane >> 4;
    f32x4 acc[4] = {{0,0,0,0},{0,0,0,0},{0,0,0,0},{0,0,0,0}};
    const us* Brow = wfcb + (size_t)(nt*16 + r)*DEC_ + g*8;
    const us* As   = s_h + r*520 + g*8;
#pragma unroll
    for (int k0 = 0; k0 < DEC_; k0 += 64) {
        short8 b0 = *(const short8*)(Brow + k0);
        short8 b1 = *(const short8*)(Brow + k0 + 32);
#pragma unroll
        for (int mt = 0; mt < 4; ++mt) {
            short8 a0 = *(const short8*)(As + mt*16*520 + k0);
            short8 a1 = *(const short8*)(As + mt*16*520 + k0 + 32);
            acc[mt] = __builtin_amdgcn_mfma_f32_16x16x32_bf16(a0, b0, acc[mt], 0, 0, 0);
            acc[mt] = __builtin_amdgcn_mfma_f32_16x16x32_bf16(a1, b1, acc[mt], 0, 0, 0);
        }
    }
    const int n = nt*16 + r;
    const float bv = b_fc[n];
#pragma unroll
    for (int mt = 0; mt < 4; ++mt)
#pragma unroll
        for (int i = 0; i < 4; ++i) {
            int b = mt*16 + g*4 + i;
            outp[(size_t)b*(T_*V_) + (size_t)tt*V_ + n] = acc[mt][i] + bv;
        }
}

__global__ __launch_bounds__(TPB)
void k_persist(
    const float* __restrict__ enc, const int* __restrict__ captions,
    const float* __restrict__ emb_table,
    const float* __restrict__ W_enc_att, const float* __restrict__ b_enc_att,
    const float* __restrict__ W_dec_att, const float* __restrict__ b_dec_att,
    const float* __restrict__ w_full,
    const float* __restrict__ W_ih, const float* __restrict__ b_ih,
    const float* __restrict__ W_hh, const float* __restrict__ b_hh,
    const float* __restrict__ W_init_h, const float* __restrict__ b_init_h,
    const float* __restrict__ W_init_c, const float* __restrict__ b_init_c,
    const float* __restrict__ W_fc, const float* __restrict__ b_fc,
    us* encb, us* wencb, us* wdecb, us* wfcb, us* wcat2, us* wembW,
    us* winitb, us* xembA, us* att1b, us* hbuf, us* xcatb, us* meanbb,
    float* cst, float* att2G, float* gp, float* gpe, float* bsum,
    unsigned* flags, float* outp, float* outa)
{
    __shared__ us s_stage[64 * 520];          // staging / fold buffer (66.5 KB)
    __shared__ us s_wb[64 * 328];             // persistent wcat2 slice (41 KB)
    __shared__ us s_wd[16 * 520];             // persistent wdec slice (16.6 KB, bid<32)
    __shared__ float s_e[P_];
    __shared__ float s_al[P_];
    __shared__ float s_red[32];

    const int tid = threadIdx.x, bid = blockIdx.x;
    const int gtid = bid * TPB + tid;
    const int wid  = gtid >> 6;
    const int w    = tid >> 6;
    const int lane = tid & 63;
    unsigned tok = 0;
    float creg = 0.f;                          // persistent LSTM cell state
    us* const hb0 = hbuf;                      // h(t) for even t
    us* const hb1 = hbuf + (size_t)B_ * DEC_;  // h(t) for odd t; h0 lives here
    unsigned* const aflags = flags + (NBLK + 16) * FSTR;   // att2 producer flags (32)

    // ---------------- S0a: bf16 casts + bias-sum + mean + xembA gather ----------------
    for (int i = gtid; i < B_*P_*ENC_/8; i += NT) cvt8(enc + (size_t)i*8, encb + (size_t)i*8);
    for (int i = gtid; i < ATT_*ENC_/8; i += NT) cvt8(W_enc_att + (size_t)i*8, wencb + (size_t)i*8);
    for (int i = gtid; i < ATT_*DEC_/8; i += NT) cvt8(W_dec_att + (size_t)i*8, wdecb + (size_t)i*8);
    for (int i = gtid; i < V_*DEC_/8;   i += NT) cvt8(W_fc + (size_t)i*8, wfcb + (size_t)i*8);
    for (int i = gtid; i < G4_*XK2_/8;  i += NT) {     // wcat2: [n][ctx2048|h512]
        int n = (i*8) / XK2_, k = (i*8) % XK2_;
        const float* src = (k < ENC_) ? (W_ih + (size_t)n*KIH_ + EMB_ + k)
                                      : (W_hh + (size_t)n*DEC_ + (k - ENC_));
        cvt8(src, wcat2 + (size_t)i*8);
    }
    for (int i = gtid; i < G4_*EMB_/8;  i += NT)       // wembW: W_ih emb part
        cvt8(W_ih + ((size_t)((i*8) / EMB_))*KIH_ + ((i*8) % EMB_), wembW + (size_t)i*8);
    for (int i = gtid; i < 1024*ENC_/8; i += NT) {
        int n = (i*8) >> 11, k = (i*8) & (ENC_ - 1);
        const float* src = (n < 512) ? (W_init_h + (size_t)n*ENC_ + k)
                                     : (W_init_c + (size_t)(n-512)*ENC_ + k);
        cvt8(src, winitb + (size_t)i*8);
    }
    for (int i = gtid; i < T_*B_*EMB_/8; i += NT) {    // xembA row r = t*64+b
        int r = i >> 6, c8 = i & 63;
        int t = r >> 6, b = r & 63;
        int cap = captions[b*MAXLEN_ + t];
        cvt8(emb_table + (size_t)cap*EMB_ + c8*8, xembA + (size_t)r*EMB_ + c8*8);
    }
    if (gtid < G4_) bsum[gtid] = b_ih[gtid] + b_hh[gtid];
    if (gtid < B_*ENC_) {
        int b = gtid >> 11, e = gtid & (ENC_ - 1);
        const float* base = enc + (size_t)b*P_*ENC_ + e;
        float s = 0.f;
        for (int p = 0; p < P_; ++p) s += base[(size_t)p*ENC_];
        meanbb[gtid] = f2bf(s * (1.f / P_));
    }
    gbar<true>(flags, ++tok);

    // ---------------- S0b: h0/c0 (256 tasks) + gpe GEMM (1856 tasks) ----------------
    for (int task = wid; task < 256 + 1856; task += NW) {
        const int r = lane & 15, g = lane >> 4;
        if (task < 256) {
            const int mt = task & 3, nt = task >> 2;
            const int m0 = mt*16, n0 = nt*16;
            const us* Ar = meanbb + (size_t)(m0 + r)*ENC_ + g*8;
            const us* Br = winitb + (size_t)(n0 + r)*ENC_ + g*8;
            f32x4 acc0 = {0,0,0,0}, acc1 = {0,0,0,0};
#pragma unroll 4
            for (int k0 = 0; k0 < ENC_; k0 += 64) {
                acc0 = __builtin_amdgcn_mfma_f32_16x16x32_bf16(
                    *(const short8*)(Ar + k0), *(const short8*)(Br + k0), acc0, 0, 0, 0);
                acc1 = __builtin_amdgcn_mfma_f32_16x16x32_bf16(
                    *(const short8*)(Ar + k0 + 32), *(const short8*)(Br + k0 + 32), acc1, 0, 0, 0);
            }
            const int n = n0 + r;
            if (n < 512) {
                float bv = b_init_h[n];
#pragma unroll
                for (int i = 0; i < 4; ++i) {
                    int b = m0 + g*4 + i;
                    unsigned hv = f2bf(acc0[i] + acc1[i] + bv);
                    st2cc(hb1 + b*DEC_ + n, hv);
                    st2cc(xcatb + (size_t)b*XK2_ + ENC_ + n, hv);
                }
            } else {
                int d = n - 512;
                float bv = b_init_c[d];
#pragma unroll
                for (int i = 0; i < 4; ++i)
                    st4cc(cst + (m0 + g*4 + i)*DEC_ + d,
                          __float_as_uint(acc0[i] + acc1[i] + bv));
            }
        } else {
            // gpe = xembA @ wembW^T + bsum   (M=1856, N=2048, K=512), 64x32 tiles
            const int q = task - 256;
            const int m0 = (q >> 6) * 64, n0 = (q & 63) * 32;
            f32x4 acc[4][2] = {};
            const us* Ab = xembA + (size_t)(m0 + r)*EMB_ + g*8;
            const us* Bb = wembW + (size_t)(n0 + r)*EMB_ + g*8;
#pragma unroll 2
            for (int k0 = 0; k0 < EMB_; k0 += 32) {
                short8 af[4], bfr[2];
#pragma unroll
                for (int mi = 0; mi < 4; ++mi)
                    af[mi] = *(const short8*)(Ab + (size_t)mi*16*EMB_ + k0);
#pragma unroll
                for (int nj = 0; nj < 2; ++nj)
                    bfr[nj] = *(const short8*)(Bb + (size_t)nj*16*EMB_ + k0);
#pragma unroll
                for (int mi = 0; mi < 4; ++mi)
#pragma unroll
                    for (int nj = 0; nj < 2; ++nj)
                        acc[mi][nj] = __builtin_amdgcn_mfma_f32_16x16x32_bf16(
                            af[mi], bfr[nj], acc[mi][nj], 0, 0, 0);
            }
#pragma unroll
            for (int mi = 0; mi < 4; ++mi)
#pragma unroll
                for (int nj = 0; nj < 2; ++nj) {
                    int n = n0 + nj*16 + r;
                    float bv = bsum[n];
#pragma unroll
                    for (int i = 0; i < 4; ++i) {
                        int m = m0 + mi*16 + g*4 + i;
                        gpe[(size_t)m*G4_ + n] = acc[mi][nj][i] + bv;
                    }
                }
        }
    }
    gbar<true>(flags, ++tok);

    // ---------------- S0c: att1 (3136) + att2-init (128) ----------------
    for (int task = wid; task < 3264; task += NW) {
        const int r = lane & 15, g = lane >> 4;
        if (task < 3136) {
            int mt = task >> 4, nt2 = task & 15;
            int m0 = mt*64, n0 = nt2*32;
            f32x4 acc[4][2] = {};
            const us* Ab = encb + (size_t)(m0 + r)*ENC_ + g*8;
            const us* Bb = wencb + (size_t)(n0 + r)*ENC_ + g*8;
#pragma unroll 2
            for (int k0 = 0; k0 < ENC_; k0 += 32) {
                short8 af[4], bfr[2];
#pragma unroll
                for (int mi = 0; mi < 4; ++mi)
                    af[mi] = *(const short8*)(Ab + (size_t)mi*16*ENC_ + k0);
#pragma unroll
                for (int nj = 0; nj < 2; ++nj)
                    bfr[nj] = *(const short8*)(Bb + (size_t)nj*16*ENC_ + k0);
#pragma unroll
                for (int mi = 0; mi < 4; ++mi)
#pragma unroll
                    for (int nj = 0; nj < 2; ++nj)
                        acc[mi][nj] = __builtin_amdgcn_mfma_f32_16x16x32_bf16(
                            af[mi], bfr[nj], acc[mi][nj], 0, 0, 0);
            }
#pragma unroll
            for (int mi = 0; mi < 4; ++mi)
#pragma unroll
                for (int nj = 0; nj < 2; ++nj) {
                    int n = n0 + nj*16 + r;
                    float bv = b_enc_att[n];
#pragma unroll
                    for (int i = 0; i < 4; ++i) {
                        int m = m0 + mi*16 + g*4 + i;
                        att1b[(size_t)m*ATT_ + n] = f2bf(acc[mi][nj][i] + bv);
                    }
                }
        } else {
            int q = task - 3136;
            int nt = q >> 2, mt = q & 3;
            const us* Ar = hb1 + (size_t)(mt*16 + r)*DEC_ + g*8;
            const us* Br = wdecb + (size_t)(nt*16 + r)*DEC_ + g*8;
            f32x4 acc0 = {0,0,0,0}, acc1 = {0,0,0,0};
#pragma unroll 4
            for (int k0 = 0; k0 < DEC_; k0 += 64) {
                short8 a0, a1, dum;
                ld16cc_x3(Ar + k0, Ar + k0 + 32, Ar + k0, &a0, &a1, &dum);
                acc0 = __builtin_amdgcn_mfma_f32_16x16x32_bf16(
                    a0, *(const short8*)(Br + k0), acc0, 0, 0, 0);
                acc1 = __builtin_amdgcn_mfma_f32_16x16x32_bf16(
                    a1, *(const short8*)(Br + k0 + 32), acc1, 0, 0, 0);
            }
            int n = nt*16 + r;
            float bv = b_dec_att[n];
#pragma unroll
            for (int i = 0; i < 4; ++i)
                st4cc(att2G + (size_t)(mt*16 + g*4 + i)*ATT_ + n,
                      __float_as_uint(acc0[i] + acc1[i] + bv));
        }
    }
    gbar<true>(flags, ++tok);

    // ---- pre-loop: persistent weight staging + creg load -------------------
    {
        const int z = bid >> 5, nb = bid & 31;
        for (int c = tid; c < 2560; c += TPB) {
            int row = c / 40, col8 = c % 40;
            *(short8*)(s_wb + row*328 + col8*8) =
                *(const short8*)(wcat2 + (size_t)(nb*64 + row)*XK2_ + (size_t)z*320 + col8*8);
        }
        if (bid < 32)
            for (int c = tid; c < 1024; c += TPB) {
                int row = c >> 6, col8 = c & 63;
                *(short8*)(s_wd + row*520 + col8*8) =
                    *(const short8*)(wdecb + (size_t)(bid*16 + row)*DEC_ + col8*8);
            }
        if (tid < 128) creg = __uint_as_float(ld4cc(cst + bid*128 + tid));
        __syncthreads();
    }
    // loop-invariant score weights
    const float4 w0v = *(const float4*)(w_full + lane*8);
    const float4 w1v = *(const float4*)(w_full + lane*8 + 4);

    // ================= decode loop: 3 barriers + att2 flag wait =================
    for (int t = 0; t < T_; ++t) {
        // ---- E: wait att2(t-1) flags; scores + softmax + ctx ----
        {
            if (t > 0) {
                if (tid < 32) {
                    while (__hip_atomic_load(&aflags[tid * FSTR], __ATOMIC_RELAXED,
                                             __HIP_MEMORY_SCOPE_AGENT) < (unsigned)t)
                        __builtin_amdgcn_s_sleep(1);
                }
                __syncthreads();
            }
            const int b = bid & 63, cc = bid >> 6;
            f32x4 a2lo, a2hi;
            const float* ap = att2G + (size_t)b*ATT_ + lane*8;
            ldf8cc(ap, ap + 4, &a2lo, &a2hi);
            const us* a1base = att1b + (size_t)b*P_*ATT_ + lane*8;
            for (int p = w; p < P_; p += 32) {
                const int p2 = p + 16;
                short8 v0 = *(const short8*)(a1base + (size_t)p*ATT_);
                short8 v1 = (p2 < P_) ? *(const short8*)(a1base + (size_t)p2*ATT_) : v0;
                float acc0 = score8(v0, a2lo, a2hi, w0v, w1v);
                float acc1 = score8(v1, a2lo, a2hi, w0v, w1v);
                acc0 = wredsum(acc0);
                acc1 = wredsum(acc1);
                if (lane == 0) {
                    s_e[p] = acc0;
                    if (p2 < P_) s_e[p2] = acc1;
                }
            }
            __syncthreads();
            float v = (tid < P_) ? s_e[tid] : -3.4e38f;
            float mx = v;
#pragma unroll
            for (int o = 32; o > 0; o >>= 1) mx = fmaxf(mx, __shfl_xor(mx, o));
            if (lane == 0) s_red[w] = mx;
            __syncthreads();
            mx = s_red[0];
#pragma unroll
            for (int j = 1; j < 16; ++j) mx = fmaxf(mx, s_red[j]);
            float ev = (tid < P_) ? expf(v - mx) : 0.f;
            float sm = wredsum(ev);
            if (lane == 0) s_red[16 + w] = sm;
            __syncthreads();
            float tot = 0.f;
#pragma unroll
            for (int j = 0; j < 16; ++j) tot += s_red[16 + j];
            if (tid < P_) {
                float al = ev / tot;
                s_al[tid] = al;
                if (cc == 0) outa[((size_t)b*T_ + t)*P_ + tid] = al;
            }
            __syncthreads();
            // ctx: thread = (sq = w, cpl = lane): cols cc*512 + cpl*8, p = sq + 16i
            float a[8] = {};
            const us* ep = encb + (size_t)b*P_*ENC_ + cc*512 + lane*8;
            for (int p = w; p < P_; p += 16) {
                short8 vv = *(const short8*)(ep + (size_t)p*ENC_);
                float al = s_al[p];
#pragma unroll
                for (int j = 0; j < 8; ++j) a[j] += al * bf2f((us)vv[j]);
            }
            float* s_accf = (float*)s_stage;   // 16 x 512 fold buffer
            {
                f32x4 lo = {a[0],a[1],a[2],a[3]}, hi = {a[4],a[5],a[6],a[7]};
                *(f32x4*)(s_accf + w*512 + lane*8)     = lo;
                *(f32x4*)(s_accf + w*512 + lane*8 + 4) = hi;
            }
            __syncthreads();
            if (tid < 256) {
                int c2 = tid*2;
                float s0 = 0.f, s1 = 0.f;
#pragma unroll
                for (int q = 0; q < 16; ++q) {
                    s0 += s_accf[q*512 + c2];
                    s1 += s_accf[q*512 + c2 + 1];
                }
                unsigned pk = (unsigned)f2bf(s0) | ((unsigned)f2bf(s1) << 16);
                st4cc(xcatb + (size_t)b*XK2_ + cc*512 + c2, pk);
            }
            __syncthreads();
        }
        gbar<false>(flags, ++tok);

        // ---- B: gates split-K=8 (320/z). xcat slice -> LDS; weights LDS-resident ----
        {
            const int z = bid >> 5;
            {
                short8 v0, v1, v2;
                int c0 = tid, c1 = tid + 1024, c2i = tid + 2048;
                const us* p0 = xcatb + (size_t)(c0/40)*XK2_ + z*320 + (c0%40)*8;
                const us* p1 = xcatb + (size_t)(c1/40)*XK2_ + z*320 + (c1%40)*8;
                bool has2 = c2i < 2560;
                const us* p2 = has2 ? xcatb + (size_t)(c2i/40)*XK2_ + z*320 + (c2i%40)*8 : p0;
                ld16cc_x3(p0, p1, p2, &v0, &v1, &v2);
                *(short8*)(s_stage + (c0/40)*328 + (c0%40)*8) = v0;
                *(short8*)(s_stage + (c1/40)*328 + (c1%40)*8) = v1;
                if (has2) *(short8*)(s_stage + (c2i/40)*328 + (c2i%40)*8) = v2;
            }
            __syncthreads();
            const int nt = (bid & 31)*4 + (w >> 2), mt = w & 3;
            const int r = lane & 15, g = lane >> 4;
            const us* sxr = s_stage + (mt*16 + r)*328 + g*8;
            const us* Br  = s_wb + ((w >> 2)*16 + r)*328 + g*8;
            f32x4 acc0 = {0,0,0,0}, acc1 = {0,0,0,0};
#pragma unroll
            for (int k0 = 0; k0 < 320; k0 += 64) {
                acc0 = __builtin_amdgcn_mfma_f32_16x16x32_bf16(
                    *(const short8*)(sxr + k0), *(const short8*)(Br + k0), acc0, 0, 0, 0);
                acc1 = __builtin_amdgcn_mfma_f32_16x16x32_bf16(
                    *(const short8*)(sxr + k0 + 32), *(const short8*)(Br + k0 + 32), acc1, 0, 0, 0);
            }
            const int n = nt*16 + r;
#pragma unroll
            for (int i = 0; i < 4; ++i) {
                int m = mt*16 + g*4 + i;
                st4cc(gp + ZS_*z + (size_t)m*G4_ + n, __float_as_uint(acc0[i] + acc1[i]));
            }
            __syncthreads();
        }
        gbar<false>(flags, ++tok);

        // ---- C: LSTM. z-reduce via 512 threads -> LDS; c-state in registers ----
        {
            float* sg = (float*)s_stage;        // [4 gates][128 cells]
            if (tid < 512) {
                const int cell = tid & 127, gate = tid >> 7;
                const int idx = bid*128 + cell;
                const int b = idx >> 9, d = idx & 511;
                const float* gz = gp + (size_t)b*G4_ + gate*512 + d;
                float vz[8];
                ld4cc_x8(gz, gz + ZS_, gz + 2*ZS_, gz + 3*ZS_,
                         gz + 4*ZS_, gz + 5*ZS_, gz + 6*ZS_, gz + 7*ZS_, vz);
                sg[tid] = ((vz[0]+vz[1]) + (vz[2]+vz[3])) + ((vz[4]+vz[5]) + (vz[6]+vz[7]));
            }
            __syncthreads();
            if (tid < 128) {
                const int idx = bid*128 + tid;
                const int b = idx >> 9, d = idx & 511;
                const float* ge = gpe + ((size_t)(t*B_ + b))*G4_ + d;
                float gi = sg[tid]       + ge[0];
                float gf = sg[128 + tid] + ge[512];
                float gg = sg[256 + tid] + ge[1024];
                float go = sg[384 + tid] + ge[1536];
                float si = 1.f / (1.f + expf(-gi));
                float sf = 1.f / (1.f + expf(-gf));
                float so = 1.f / (1.f + expf(-go));
                float cn = sf * creg + si * tanhf(gg);
                creg = cn;
                float hn = so * tanhf(cn);
                unsigned hv = f2bf(hn);
                us* hnew = (t & 1) ? hb1 : hb0;
                st2cc(hnew + idx, hv);
                st2cc(xcatb + (size_t)b*XK2_ + ENC_ + d, hv);
            }
        }
        gbar<false>(flags, ++tok);

        // ---- post-C: att2(t) producers (bid<32, flag publish); preds(t-1)
        //      on bid>=32, fully unsynchronized ----
        if (bid < 32) {
            if (t != T_ - 1) {
                const us* hbn = (t & 1) ? hb1 : hb0;
                short8 v0, v1, v2, v3;
                int c0 = tid, c1 = tid + 1024, c2i = tid + 2048, c3 = tid + 3072;
                ld16cc_x4(hbn + (c0>>6)*DEC_ + (c0&63)*8, hbn + (c1>>6)*DEC_ + (c1&63)*8,
                          hbn + (c2i>>6)*DEC_ + (c2i&63)*8, hbn + (c3>>6)*DEC_ + (c3&63)*8,
                          &v0, &v1, &v2, &v3);
                *(short8*)(s_stage + (c0>>6)*520 + (c0&63)*8) = v0;
                *(short8*)(s_stage + (c1>>6)*520 + (c1&63)*8) = v1;
                *(short8*)(s_stage + (c2i>>6)*520 + (c2i&63)*8) = v2;
                *(short8*)(s_stage + (c3>>6)*520 + (c3&63)*8) = v3;
                __syncthreads();
                if (w < 4) {
                    const int r = lane & 15, g = lane >> 4;
                    const us* As = s_stage + (w*16 + r)*520 + g*8;
                    const us* Bs = s_wd + r*520 + g*8;
                    f32x4 acc0 = {0,0,0,0}, acc1 = {0,0,0,0};
#pragma unroll
                    for (int k0 = 0; k0 < DEC_; k0 += 64) {
                        acc0 = __builtin_amdgcn_mfma_f32_16x16x32_bf16(
                            *(const short8*)(As + k0), *(const short8*)(Bs + k0), acc0, 0, 0, 0);
                        acc1 = __builtin_amdgcn_mfma_f32_16x16x32_bf16(
                            *(const short8*)(As + k0 + 32), *(const short8*)(Bs + k0 + 32), acc1, 0, 0, 0);
                    }
                    const int n = bid*16 + r;
                    float bv = b_dec_att[n];
#pragma unroll
                    for (int i = 0; i < 4; ++i)
                        st4cc(att2G + (size_t)(w*16 + g*4 + i)*ATT_ + n,
                              __float_as_uint(acc0[i] + acc1[i] + bv));
                }
                asm volatile("s_waitcnt vmcnt(0)" ::: "memory");
                __syncthreads();
                if (tid == 0)
                    __hip_atomic_store(&aflags[bid * FSTR], (unsigned)(t + 1),
                                       __ATOMIC_RELAXED, __HIP_MEMORY_SCOPE_AGENT);
            }
        } else if (t > 0) {
            // preds(t-1): consumer is global output only, no sync needed
            const us* hbo = (t & 1) ? hb0 : hb1;   // h(t-1), stable
            short8 v0, v1, v2, v3;
            int c0 = tid, c1 = tid + 1024, c2i = tid + 2048, c3 = tid + 3072;
            ld16cc_x4(hbo + (c0>>6)*DEC_ + (c0&63)*8, hbo + (c1>>6)*DEC_ + (c1&63)*8,
                      hbo + (c2i>>6)*DEC_ + (c2i&63)*8, hbo + (c3>>6)*DEC_ + (c3&63)*8,
                      &v0, &v1, &v2, &v3);
            *(short8*)(s_stage + (c0>>6)*520 + (c0&63)*8) = v0;
            *(short8*)(s_stage + (c1>>6)*520 + (c1&63)*8) = v1;
            *(short8*)(s_stage + (c2i>>6)*520 + (c2i&63)*8) = v2;
            *(short8*)(s_stage + (c3>>6)*520 + (c3&63)*8) = v3;
            __syncthreads();
            const int tq = (bid - 32)*3 + w;
            if (w < 3 && tq < NPT)
                preds_task(s_stage, wfcb, b_fc, outp, tq, t - 1, lane);
            __syncthreads();
        }
    }

    // ---- tail: preds(T-1), 16 tasks/block on blocks 0..39 (no barrier) ----
    if (bid < 40) {
        __syncthreads();
        const us* hbn = ((T_ - 1) & 1) ? hb1 : hb0;
        {
            short8 v0, v1, v2, v3;
            int c0 = tid, c1 = tid + 1024, c2i = tid + 2048, c3 = tid + 3072;
            ld16cc_x4(hbn + (c0>>6)*DEC_ + (c0&63)*8, hbn + (c1>>6)*DEC_ + (c1&63)*8,
                      hbn + (c2i>>6)*DEC_ + (c2i&63)*8, hbn + (c3>>6)*DEC_ + (c3&63)*8,
                      &v0, &v1, &v2, &v3);
            *(short8*)(s_stage + (c0>>6)*520 + (c0&63)*8) = v0;
            *(short8*)(s_stage + (c1>>6)*520 + (c1&63)*8) = v1;
            *(short8*)(s_stage + (c2i>>6)*520 + (c2i&63)*8) = v2;
            *(short8*)(s_stage + (c3>>6)*520 + (c3&63)*8) = v3;
        }
        __syncthreads();
        const int tq = bid*16 + w;
        if (tq < NPT)
            preds_task(s_stage, wfcb, b_fc, outp, tq, T_ - 1, lane);
    }
}

// ---------------------------------------------------------------------------
extern "C" void kernel_launch(void* const* d_in, const int* in_sizes, int n_in,
                              void* d_out, int out_size, void* d_ws, size_t ws_size,
                              hipStream_t stream) {
    const float* enc       = (const float*)d_in[0];
    const int*   captions  = (const int*)d_in[1];
    const float* emb_table = (const float*)d_in[3];
    const float* W_enc_att = (const float*)d_in[4];
    const float* b_enc_att = (const float*)d_in[5];
    const float* W_dec_att = (const float*)d_in[6];
    const float* b_dec_att = (const float*)d_in[7];
    const float* w_full    = (const float*)d_in[8];
    const float* W_ih      = (const float*)d_in[10];
    const float* b_ih      = (const float*)d_in[11];
    const float* W_hh      = (const float*)d_in[12];
    const float* b_hh      = (const float*)d_in[13];
    const float* W_init_h  = (const float*)d_in[14];
    const float* b_init_h  = (const float*)d_in[15];
    const float* W_init_c  = (const float*)d_in[16];
    const float* b_init_c  = (const float*)d_in[17];
    const float* W_fc      = (const float*)d_in[18];
    const float* b_fc      = (const float*)d_in[19];

    char* ws = (char*)d_ws;
    size_t off = 0;
    auto alloc = [&](size_t bytes) {
        void* p = ws + off;
        off = (off + bytes + 255) & ~(size_t)255;
        return p;
    };
    us* encb   = (us*)alloc((size_t)B_ * P_ * ENC_ * 2);
    us* wencb  = (us*)alloc((size_t)ATT_ * ENC_ * 2);
    us* wdecb  = (us*)alloc((size_t)ATT_ * DEC_ * 2);
    us* wfcb   = (us*)alloc((size_t)V_ * DEC_ * 2);
    us* wcat2  = (us*)alloc((size_t)G4_ * XK2_ * 2);
    us* wembW  = (us*)alloc((size_t)G4_ * EMB_ * 2);
    us* winitb = (us*)alloc((size_t)1024 * ENC_ * 2);
    us* xembA  = (us*)alloc((size_t)T_ * B_ * EMB_ * 2);
    us* att1b  = (us*)alloc((size_t)B_ * P_ * ATT_ * 2);
    us* hbuf   = (us*)alloc((size_t)2 * B_ * DEC_ * 2);   // double-buffered h
    us* xcatb  = (us*)alloc((size_t)B_ * XK2_ * 2);
    us* meanbb = (us*)alloc((size_t)B_ * ENC_ * 2);
    float* cst   = (float*)alloc((size_t)B_ * DEC_ * 4);
    float* att2G = (float*)alloc((size_t)B_ * ATT_ * 4);
    float* gp    = (float*)alloc((size_t)B_ * G4_ * 8 * 4);
    float* gpe   = (float*)alloc((size_t)T_ * B_ * G4_ * 4);
    float* bsum  = (float*)alloc((size_t)G4_ * 4);
    unsigned* flags = (unsigned*)alloc((size_t)(NBLK + 64) * FSTR * 4);

    float* outp = (float*)d_out;
    float* outa = outp + (size_t)B_ * T_ * V_;

    hipMemsetAsync(flags, 0, (NBLK + 64) * FSTR * sizeof(unsigned), stream);
    k_persist<<<NBLK, TPB, 0, stream>>>(
        enc, captions, emb_table, W_enc_att, b_enc_att, W_dec_att, b_dec_att,
        w_full, W_ih, b_ih, W_hh, b_hh, W_init_h, b_init_h, W_init_c, b_init_c,
        W_fc, b_fc,
        encb, wencb, wdecb, wfcb, wcat2, wembW, winitb, xembA, att1b, hbuf, xcatb,
        meanbb, cst, att2G, gp, gpe, bsum, flags, outp, outa);
}